// Round 10
// baseline (554.756 us; speedup 1.0000x reference)
//
#include <hip/hip_runtime.h>
#include <hip/hip_bf16.h>

#define NE 800000
#define NN 50000
#define NG 16
#define ETOT (NE + NN)

typedef unsigned short u16;
typedef __attribute__((ext_vector_type(8))) short short8;
typedef __attribute__((ext_vector_type(4))) float float4v;

__device__ __forceinline__ float b2f(u16 u) {
  return __uint_as_float(((unsigned)u) << 16);
}
__device__ __forceinline__ u16 f2b(float f) {
  __hip_bfloat16 b = __float2bfloat16(f);
  return *(u16*)&b;
}
__device__ __forceinline__ void cv8(uint4 v, float* o) {
  o[0] = __uint_as_float(v.x << 16);
  o[1] = __uint_as_float(v.x & 0xFFFF0000u);
  o[2] = __uint_as_float(v.y << 16);
  o[3] = __uint_as_float(v.y & 0xFFFF0000u);
  o[4] = __uint_as_float(v.z << 16);
  o[5] = __uint_as_float(v.z & 0xFFFF0000u);
  o[6] = __uint_as_float(v.w << 16);
  o[7] = __uint_as_float(v.w & 0xFFFF0000u);
}
__device__ __forceinline__ unsigned pk2(float a, float b) {
  return (unsigned)f2b(a) | ((unsigned)f2b(b) << 16);
}
__device__ __forceinline__ unsigned f2key(float f) {
  unsigned u = __float_as_uint(f);
  return (u & 0x80000000u) ? ~u : (u | 0x80000000u);
}
__device__ __forceinline__ float key2f(unsigned k) {
  unsigned u = (k & 0x80000000u) ? (k ^ 0x80000000u) : ~k;
  return __uint_as_float(u);
}
__device__ __forceinline__ int plaus(unsigned h) {
  unsigned eh = (h >> 7) & 0xFF;
  return (h == 0) || (eh >= 100 && eh <= 140);
}
__device__ __forceinline__ float lrelu(float v) {
  return (v > 0.f) ? v : 0.2f * v;
}

#define NDEG 8  // deg privatization copies
#define LOG2E 1.4426950408889634f

// ========== D1: zero accumulator region + dtype detect (block 0; NO fence) ==========
__global__ __launch_bounds__(256) void k_init(uint4* __restrict__ zbase, int zcnt16,
                                              const unsigned* __restrict__ a,
                                              const unsigned* __restrict__ b,
                                              const unsigned* __restrict__ c,
                                              int* __restrict__ flags) {
  uint4 z = {0, 0, 0, 0};
  for (int i = blockIdx.x * 256 + threadIdx.x; i < zcnt16; i += gridDim.x * 256)
    zbase[i] = z;
  if (blockIdx.x != 0) return;
  __shared__ int cnt[3];
  if (threadIdx.x < 3) cnt[threadIdx.x] = 0;
  __syncthreads();
  const unsigned* arr[3] = {a, b, c};
  for (int k = 0; k < 3; k++) {
    int ok = 0;
    for (int i = threadIdx.x; i < 4096; i += 256) {
      unsigned w = arr[k][i];
      ok += (plaus(w & 0xFFFFu) && plaus(w >> 16)) ? 1 : 0;
    }
    atomicAdd(&cnt[k], ok);
  }
  __syncthreads();
  if (threadIdx.x == 0) {
    int f0 = cnt[0] > 2048, f1 = cnt[1] > 2048, f2 = cnt[2] > 2048;
    flags[0] = f0;
    flags[1] = f1;
    flags[2] = f2;
    flags[3] = f0 && f1 && f2;
  }
}

// ========== D2a: deg scatter ONLY (8-way privatized; tiny waves, max TLP) ==========
__global__ __launch_bounds__(256) void k_hist(const int* __restrict__ ei,
                                              int* __restrict__ deg8) {
  int gt = blockIdx.x * 256 + threadIdx.x;
  if (gt >= ETOT) return;
  int dst = (gt < NE) ? ei[NE + gt] : gt - NE;
  atomicAdd(&deg8[(blockIdx.x & (NDEG - 1)) * NN + dst], 1);
}

// ========== D2: edge_attr colsums + x hi/lo bf16 split (pure streaming) ==========
__global__ __launch_bounds__(256) void k_colsum_xsplit(
    const void* __restrict__ ea, const void* __restrict__ xin,
    const int* __restrict__ flg, float* __restrict__ mean_part,
    u16* __restrict__ xh, u16* __restrict__ xlo) {
  int gt = blockIdx.x * 256 + threadIdx.x;
  bool eb = flg[2] != 0;
  int col = gt & 15;
  int row = gt >> 4;
  int rstride = (gridDim.x * 256) >> 4;
  float s = 0.f;
  if (eb) {
    const u16* p = (const u16*)ea;
    for (int e = row; e < NE; e += rstride) s += b2f(p[(size_t)e * 16 + col]);
  } else {
    const float* p = (const float*)ea;
    for (int e = row; e < NE; e += rstride) s += p[(size_t)e * 16 + col];
  }
  __shared__ float ls[256];
  ls[threadIdx.x] = s;
  __syncthreads();
  if (threadIdx.x < 16) {
    float t = 0.f;
    for (int i = threadIdx.x; i < 256; i += 16) t += ls[i];
    atomicAdd(&mean_part[(blockIdx.x & 63) * 16 + threadIdx.x], t);
  }
  // ---- x hi/lo split (only when x is f32) ----
  if (flg[0] == 0) {
    const float4* xp4 = (const float4*)xin;
    const int nch = NN * 32;  // 1.6M float4 chunks
    int stride = gridDim.x * 256;
    for (int i = gt; i < nch; i += stride) {
      float4 v = xp4[i];
      u16 h0 = f2b(v.x), h1 = f2b(v.y), h2 = f2b(v.z), h3 = f2b(v.w);
      u16 l0 = f2b(v.x - b2f(h0));
      u16 l1 = f2b(v.y - b2f(h1));
      u16 l2 = f2b(v.z - b2f(h2));
      u16 l3 = f2b(v.w - b2f(h3));
      uint2 ho, lo2;
      ho.x = (unsigned)h0 | ((unsigned)h1 << 16);
      ho.y = (unsigned)h2 | ((unsigned)h3 << 16);
      lo2.x = (unsigned)l0 | ((unsigned)l1 << 16);
      lo2.y = (unsigned)l2 | ((unsigned)l3 << 16);
      *(uint2*)(xh + (size_t)i * 4) = ho;
      *(uint2*)(xlo + (size_t)i * 4) = lo2;
    }
  }
}

#define SCAN_NT ((NN + 1023) / 1024)  // 49

// ========== D2b: per-tile degree sums (49 blocks) ==========
__global__ __launch_bounds__(256) void k_scansum(const int* __restrict__ deg8,
                                                 const float* __restrict__ mean_part,
                                                 float* __restrict__ mean_sums,
                                                 int* __restrict__ tile_tot) {
  int t = threadIdx.x;
  if (blockIdx.x == 0 && t < 16) {
    float s = 0.f;
#pragma unroll
    for (int j = 0; j < 64; j++) s += mean_part[j * 16 + t];
    mean_sums[t] = s;
  }
  int lane = t & 63;
  int wv = t >> 6;
  int idx = blockIdx.x * 1024 + t * 4;
  int s4 = 0;
  if (idx + 3 < NN) {
#pragma unroll
    for (int c = 0; c < NDEG; c++) {
      int4 dc = *(const int4*)(deg8 + c * NN + idx);
      s4 += dc.x + dc.y + dc.z + dc.w;
    }
  } else {
#pragma unroll
    for (int c = 0; c < NDEG; c++) {
      if (idx + 0 < NN) s4 += deg8[c * NN + idx + 0];
      if (idx + 1 < NN) s4 += deg8[c * NN + idx + 1];
      if (idx + 2 < NN) s4 += deg8[c * NN + idx + 2];
      if (idx + 3 < NN) s4 += deg8[c * NN + idx + 3];
    }
  }
  int r = s4;
#pragma unroll
  for (int ofs = 1; ofs < 64; ofs <<= 1) r += __shfl_xor(r, ofs, 64);
  __shared__ int wsum[4];
  if (lane == 0) wsum[wv] = r;
  __syncthreads();
  if (t == 0) tile_tot[blockIdx.x] = wsum[0] + wsum[1] + wsum[2] + wsum[3];
}

// ========== D2c: prefix bases + per-tile scan + start/cursor write (49 blocks) ==========
__global__ __launch_bounds__(256) void k_scanwrite(const int* __restrict__ deg8,
                                                   const int* __restrict__ tile_tot,
                                                   int* __restrict__ start,
                                                   int* __restrict__ cursor) {
  __shared__ int sbase;
  __shared__ int wsum[4];
  int t = threadIdx.x;
  int lane = t & 63;
  int wv = t >> 6;
  if (wv == 0) {
    int v = (lane < SCAN_NT) ? tile_tot[lane] : 0;
    int sc = v;
#pragma unroll
    for (int ofs = 1; ofs < 64; ofs <<= 1) {
      int u = __shfl_up(sc, ofs, 64);
      if (lane >= ofs) sc += u;
    }
    if (lane == (int)blockIdx.x) sbase = sc - v;
    if (blockIdx.x == 0 && lane == SCAN_NT - 1) start[NN] = sc;
  }
  int idx = blockIdx.x * 1024 + t * 4;
  int4 d = {0, 0, 0, 0};
  if (idx + 3 < NN) {
#pragma unroll
    for (int c = 0; c < NDEG; c++) {
      int4 dc = *(const int4*)(deg8 + c * NN + idx);
      d.x += dc.x; d.y += dc.y; d.z += dc.z; d.w += dc.w;
    }
  } else {
#pragma unroll
    for (int c = 0; c < NDEG; c++) {
      if (idx + 0 < NN) d.x += deg8[c * NN + idx + 0];
      if (idx + 1 < NN) d.y += deg8[c * NN + idx + 1];
      if (idx + 2 < NN) d.z += deg8[c * NN + idx + 2];
      if (idx + 3 < NN) d.w += deg8[c * NN + idx + 3];
    }
  }
  int s4 = d.x + d.y + d.z + d.w;
  int sc = s4;
#pragma unroll
  for (int ofs = 1; ofs < 64; ofs <<= 1) {
    int v = __shfl_up(sc, ofs, 64);
    if (lane >= ofs) sc += v;
  }
  if (lane == 63) wsum[wv] = sc;
  __syncthreads();
  int wbase = 0;
#pragma unroll
  for (int w = 0; w < 4; w++)
    if (w < wv) wbase += wsum[w];
  int excl = sbase + wbase + (sc - s4);
  int4 st;
  st.x = excl;
  st.y = excl + d.x;
  st.z = st.y + d.y;
  st.w = st.z + d.z;
  if (idx + 3 < NN) {
    *(int4*)(start + idx) = st;
    *(int4*)(cursor + idx) = st;
  } else {
    if (idx + 0 < NN) { start[idx + 0] = st.x; cursor[idx + 0] = st.x; }
    if (idx + 1 < NN) { start[idx + 1] = st.y; cursor[idx + 1] = st.y; }
    if (idx + 2 < NN) { start[idx + 2] = st.z; cursor[idx + 2] = st.z; }
    if (idx + 3 < NN) { start[idx + 3] = st.w; cursor[idx + 3] = st.w; }
  }
}

// ===== LDS-free split-bf16 MFMA GEMM tile =====
template <int K, int N, int RPB>
__device__ __forceinline__ void gemm_direct(
    const void* __restrict__ W, const void* __restrict__ bb, bool wb,
    const u16* __restrict__ xh, const u16* __restrict__ xlo, bool has_lo,
    u16* __restrict__ out, int tile) {
  constexpr int CT = N / 16;      // column tiles
  constexpr int WPC = 4 / CT;     // waves per column tile
  constexpr int KK = K / 32;
  int lane = threadIdx.x & 63;
  int wave = threadIdx.x >> 6;
  int col = lane & 15;
  int quad = lane >> 4;
  int ct = wave % CT;
  int rt_off = wave / CT;
  short8 bh[KK], bl[KK];
#pragma unroll
  for (int kk = 0; kk < KK; kk++) {
    short8 th, tl;
#pragma unroll
    for (int j = 0; j < 8; j++) {
      int k = kk * 32 + quad * 8 + j;
      float w = wb ? b2f(((const u16*)W)[k * N + ct * 16 + col])
                   : ((const float*)W)[k * N + ct * 16 + col];
      u16 hb = f2b(w);
      th[j] = (short)hb;
      tl[j] = (short)f2b(w - b2f(hb));
    }
    bh[kk] = th;
    bl[kk] = tl;
  }
  float bias = wb ? b2f(((const u16*)bb)[ct * 16 + col])
                  : ((const float*)bb)[ct * 16 + col];
  int rt0 = tile * RPB;
  for (int i = rt_off; i < RPB; i += WPC) {
    int rt = rt0 + i;
    int row = rt * 16 + col;
    float4v acc = {0.f, 0.f, 0.f, 0.f};
#pragma unroll
    for (int kk = 0; kk < KK; kk++) {
      short8 afh = *(const short8*)(xh + (size_t)row * K + kk * 32 + quad * 8);
      acc = __builtin_amdgcn_mfma_f32_16x16x32_bf16(afh, bh[kk], acc, 0, 0, 0);
      if (has_lo) {
        short8 afl = *(const short8*)(xlo + (size_t)row * K + kk * 32 + quad * 8);
        acc = __builtin_amdgcn_mfma_f32_16x16x32_bf16(afl, bh[kk], acc, 0, 0, 0);
      }
      if (!wb)
        acc = __builtin_amdgcn_mfma_f32_16x16x32_bf16(afh, bl[kk], acc, 0, 0, 0);
    }
#pragma unroll
    for (int r = 0; r < 4; r++) {
      int orow = rt * 16 + quad * 4 + r;
      out[(size_t)orow * N + ct * 16 + col] = f2b(acc[r] + bias);
    }
  }
}

// ========== D3: lin3 L1 (pure GEMM) ==========
template <int K, int N, int TILES, int RPB>
__global__ __launch_bounds__(256) void k_lin1(
    const void* __restrict__ xin, const u16* __restrict__ xh,
    const u16* __restrict__ xlo, const int* __restrict__ flg,
    const void* W0, const void* W1, const void* W2,
    const void* b0, const void* b1, const void* b2,
    u16* __restrict__ o0, u16* __restrict__ o1, u16* __restrict__ o2) {
  int lidx = blockIdx.x;
  int wset = lidx / TILES;
  int tile = lidx % TILES;
  bool wb = flg[1] != 0;
  bool xb = flg[0] != 0;
  const void* W = wset == 0 ? W0 : (wset == 1 ? W1 : W2);
  const void* bb = wset == 0 ? b0 : (wset == 1 ? b1 : b2);
  u16* out = wset == 0 ? o0 : (wset == 1 ? o1 : o2);
  const u16* ah = xb ? (const u16*)xin : xh;
  gemm_direct<K, N, RPB>(W, bb, wb, ah, xlo, !xb, out, tile);
}

// ========== D4: CSR build with bf16 payload (tier0/1) / eid-indirect (tier2) ==========
__global__ __launch_bounds__(256) void k_buildcsr_pay(
    const int* __restrict__ ei, const void* __restrict__ eattr,
    const int* __restrict__ flg, const float* __restrict__ mean_sums,
    int* __restrict__ cursor, int* __restrict__ csr_src,
    u16* __restrict__ ea16) {
  int e = blockIdx.x * 256 + threadIdx.x;
  if (e >= ETOT) return;
  bool eb = flg[2] != 0;
  int src, dst;
  if (e < NE) { src = ei[e]; dst = ei[NE + e]; } else { src = dst = e - NE; }
  float rec[16];
  if (e < NE) {
    if (eb) {
      const uint4* q = (const uint4*)((const u16*)eattr + (size_t)e * 16);
      cv8(q[0], rec);
      cv8(q[1], rec + 8);
    } else {
      const float* q = (const float*)eattr + (size_t)e * 16;
#pragma unroll
      for (int k = 0; k < 16; k++) rec[k] = q[k];
    }
  } else {
#pragma unroll
    for (int k = 0; k < 16; k++) rec[k] = mean_sums[k] * (1.0f / NE);
  }
  int pos = atomicAdd(&cursor[dst], 1);
  csr_src[pos] = src;
  u16 rb[16];
#pragma unroll
  for (int k = 0; k < 16; k++) rb[k] = f2b(rec[k]);
  uint4* dp = (uint4*)(ea16 + (size_t)pos * 16);
  dp[0] = *(uint4*)rb;
  dp[1] = *(uint4*)(rb + 8);
}

__global__ __launch_bounds__(256) void k_buildcsr(const int* __restrict__ ei,
                                                  int* __restrict__ cursor,
                                                  uint2* __restrict__ csr) {
  int e = blockIdx.x * 256 + threadIdx.x;
  if (e >= ETOT) return;
  int src, dst;
  if (e < NE) { src = ei[e]; dst = ei[NE + e]; } else { src = dst = e - NE; }
  int pos = atomicAdd(&cursor[dst], 1);
  uint2 r; r.x = (unsigned)src; r.y = (unsigned)e;
  csr[pos] = r;
}

// ========== D4c: EW = payload @ We GEMM (tier0 only) ==========
__global__ __launch_bounds__(256) void k_ewgemm(
    const u16* __restrict__ ea, const int* __restrict__ flg,
    const void* We1, const void* We2,
    u16* __restrict__ ew1, u16* __restrict__ ew2) {
  bool wb = flg[1] != 0;
  int lane = threadIdx.x & 63;
  int col = lane & 15;
  int quad = lane >> 4;
  short8 b1h[4], b1l[4], b2h[2], b2l[2];
#pragma unroll
  for (int ct = 0; ct < 4; ct++) {
    short8 th, tl;
#pragma unroll
    for (int j = 0; j < 8; j++) {
      int k = quad * 8 + j;
      float w = 0.f;
      if (k < 16)
        w = wb ? b2f(((const u16*)We1)[k * 64 + ct * 16 + col])
               : ((const float*)We1)[k * 64 + ct * 16 + col];
      u16 hb = f2b(w);
      th[j] = (short)hb;
      tl[j] = (short)f2b(w - b2f(hb));
    }
    b1h[ct] = th; b1l[ct] = tl;
  }
#pragma unroll
  for (int ct = 0; ct < 2; ct++) {
    short8 th, tl;
#pragma unroll
    for (int j = 0; j < 8; j++) {
      int k = quad * 8 + j;
      float w = 0.f;
      if (k < 16)
        w = wb ? b2f(((const u16*)We2)[k * 32 + ct * 16 + col])
               : ((const float*)We2)[k * 32 + ct * 16 + col];
      u16 hb = f2b(w);
      th[j] = (short)hb;
      tl[j] = (short)f2b(w - b2f(hb));
    }
    b2h[ct] = th; b2l[ct] = tl;
  }
  int nw = (gridDim.x * 256) >> 6;
  int wid = (blockIdx.x * 256 + threadIdx.x) >> 6;
  const int NT = ETOT / 16;  // 53125 exact
  for (int rt = wid; rt < NT; rt += nw) {
    int row = rt * 16 + col;
    short8 af = {0, 0, 0, 0, 0, 0, 0, 0};
    if (quad < 2) af = *(const short8*)(ea + (size_t)row * 16 + quad * 8);
#pragma unroll
    for (int ct = 0; ct < 4; ct++) {
      float4v acc = {0.f, 0.f, 0.f, 0.f};
      acc = __builtin_amdgcn_mfma_f32_16x16x32_bf16(af, b1h[ct], acc, 0, 0, 0);
      acc = __builtin_amdgcn_mfma_f32_16x16x32_bf16(af, b1l[ct], acc, 0, 0, 0);
#pragma unroll
      for (int r = 0; r < 4; r++)
        ew1[(size_t)(rt * 16 + quad * 4 + r) * 64 + ct * 16 + col] = f2b(acc[r]);
    }
#pragma unroll
    for (int ct = 0; ct < 2; ct++) {
      float4v acc = {0.f, 0.f, 0.f, 0.f};
      acc = __builtin_amdgcn_mfma_f32_16x16x32_bf16(af, b2h[ct], acc, 0, 0, 0);
      acc = __builtin_amdgcn_mfma_f32_16x16x32_bf16(af, b2l[ct], acc, 0, 0, 0);
#pragma unroll
      for (int r = 0; r < 4; r++)
        ew2[(size_t)(rt * 16 + quad * 4 + r) * 32 + ct * 16 + col] = f2b(acc[r]);
    }
  }
}

// ==== standalone lin3 (layer 2) — LDS-free; xin (h1) always bf16 ====
template <int K, int N, int RPB>
__global__ __launch_bounds__(256) void k_lin3b(
    const void* __restrict__ xin, const int* __restrict__ flg,
    const void* W0, const void* W1, const void* W2,
    const void* b0, const void* b1, const void* b2,
    u16* __restrict__ o0, u16* __restrict__ o1, u16* __restrict__ o2, int M) {
  (void)M;
  bool wb = flg[1] != 0;
  const void* W = blockIdx.y == 0 ? W0 : (blockIdx.y == 1 ? W1 : W2);
  const void* bb = blockIdx.y == 0 ? b0 : (blockIdx.y == 1 ? b1 : b2);
  u16* out = blockIdx.y == 0 ? o0 : (blockIdx.y == 1 ? o1 : o2);
  gemm_direct<K, N, RPB>(W, bb, wb, (const u16*)xin, nullptr, false, out,
                         blockIdx.x);
}

// ===== payload dots =====
__device__ __forceinline__ float dot16b(const u16* __restrict__ p,
                                        const float* __restrict__ W) {
  float ea[16];
  const uint4* q = (const uint4*)p;
  cv8(q[0], ea);
  cv8(q[1], ea + 8);
  float s = 0.f;
#pragma unroll
  for (int k = 0; k < 16; k++) s += ea[k] * W[k];
  return s;
}
__device__ __forceinline__ float dot16u(const u16* __restrict__ p,
                                        const float* __restrict__ W) {
  const uint4* q = (const uint4*)p;
  uint4 A = q[0], B = q[1];
  unsigned w0 = (unsigned)__builtin_amdgcn_readfirstlane((int)A.x);
  unsigned w1 = (unsigned)__builtin_amdgcn_readfirstlane((int)A.y);
  unsigned w2 = (unsigned)__builtin_amdgcn_readfirstlane((int)A.z);
  unsigned w3 = (unsigned)__builtin_amdgcn_readfirstlane((int)A.w);
  unsigned w4 = (unsigned)__builtin_amdgcn_readfirstlane((int)B.x);
  unsigned w5 = (unsigned)__builtin_amdgcn_readfirstlane((int)B.y);
  unsigned w6 = (unsigned)__builtin_amdgcn_readfirstlane((int)B.z);
  unsigned w7 = (unsigned)__builtin_amdgcn_readfirstlane((int)B.w);
  float s = 0.f;
  s += __uint_as_float(w0 << 16) * W[0];
  s += __uint_as_float(w0 & 0xFFFF0000u) * W[1];
  s += __uint_as_float(w1 << 16) * W[2];
  s += __uint_as_float(w1 & 0xFFFF0000u) * W[3];
  s += __uint_as_float(w2 << 16) * W[4];
  s += __uint_as_float(w2 & 0xFFFF0000u) * W[5];
  s += __uint_as_float(w3 << 16) * W[6];
  s += __uint_as_float(w3 & 0xFFFF0000u) * W[7];
  s += __uint_as_float(w4 << 16) * W[8];
  s += __uint_as_float(w4 & 0xFFFF0000u) * W[9];
  s += __uint_as_float(w5 << 16) * W[10];
  s += __uint_as_float(w5 & 0xFFFF0000u) * W[11];
  s += __uint_as_float(w6 << 16) * W[12];
  s += __uint_as_float(w6 & 0xFFFF0000u) * W[13];
  s += __uint_as_float(w7 << 16) * W[14];
  s += __uint_as_float(w7 & 0xFFFF0000u) * W[15];
  return s;
}
__device__ __forceinline__ float dot16f(const float* __restrict__ q,
                                        const float* __restrict__ W) {
  float s = 0.f;
#pragma unroll
  for (int k = 0; k < 16; k++) s += q[k] * W[k];
  return s;
}

// ===== D5/D9: fused attention + softmax gather-reduce (8-edge ILP, exp2) =====
template <int H, int C, bool PRE>
__global__ __launch_bounds__(256) void k_fusedp(
    const int* __restrict__ start, const int* __restrict__ csr_src,
    const u16* __restrict__ pay, const u16* __restrict__ ewp,
    const int* __restrict__ flg,
    const u16* __restrict__ xl, const u16* __restrict__ xr,
    const void* We, const void* att, u16* __restrict__ agg) {
  constexpr int D = H * C;
  constexpr int NPW = 64 / D;
  bool wb = flg[1] != 0;
  int lane = threadIdx.x & 63;
  int ch = lane % D;
  float Wreg[16];
  if constexpr (!PRE) {
    if (wb) {
      const u16* Wp = (const u16*)We;
#pragma unroll
      for (int k = 0; k < 16; k++) Wreg[k] = b2f(Wp[k * D + ch]);
    } else {
      const float* Wp = (const float*)We;
#pragma unroll
      for (int k = 0; k < 16; k++) Wreg[k] = Wp[k * D + ch];
    }
  }
  // fold log2(e) into att so the post-reduce exp is a bare v_exp (exp2f)
  float attv = (wb ? b2f(((const u16*)att)[ch]) : ((const float*)att)[ch]) * LOG2E;
  int wid = (blockIdx.x * 256 + threadIdx.x) >> 6;

  if constexpr (NPW == 1) {
    int node = __builtin_amdgcn_readfirstlane(wid);
    int s0 = __builtin_amdgcn_readfirstlane(start[node]);
    int s1 = __builtin_amdgcn_readfirstlane(start[node + 1]);
    float xrv = b2f(xr[(unsigned)node * D + ch]);
    float ssum = 0.f, acc = 0.f;
    int p = s0;
    for (; p + 7 < s1; p += 8) {
      int c[8];
#pragma unroll
      for (int j = 0; j < 8; j++)
        c[j] = __builtin_amdgcn_readfirstlane(csr_src[p + j]);
      float xlv[8];
#pragma unroll
      for (int j = 0; j < 8; j++) xlv[j] = b2f(xl[(unsigned)c[j] * D + ch]);
      float t[8];
#pragma unroll
      for (int j = 0; j < 8; j++) {
        float ev;
        if constexpr (PRE) ev = b2f(ewp[(size_t)(p + j) * D + ch]);
        else ev = dot16u(pay + (size_t)(p + j) * 16, Wreg);
        t[j] = lrelu(xlv[j] + xrv + ev) * attv;
      }
#pragma unroll
      for (int mk = 1; mk <= 16; mk <<= 1) {
#pragma unroll
        for (int j = 0; j < 8; j++) t[j] += __shfl_xor(t[j], mk, 64);
      }
#pragma unroll
      for (int j = 0; j < 8; j++) {
        float ex = exp2f(t[j]);
        ssum += ex;
        acc += ex * xlv[j];
      }
    }
    for (; p + 3 < s1; p += 4) {
      int c[4];
#pragma unroll
      for (int j = 0; j < 4; j++)
        c[j] = __builtin_amdgcn_readfirstlane(csr_src[p + j]);
      float xlv[4], t[4];
#pragma unroll
      for (int j = 0; j < 4; j++) xlv[j] = b2f(xl[(unsigned)c[j] * D + ch]);
#pragma unroll
      for (int j = 0; j < 4; j++) {
        float ev;
        if constexpr (PRE) ev = b2f(ewp[(size_t)(p + j) * D + ch]);
        else ev = dot16u(pay + (size_t)(p + j) * 16, Wreg);
        t[j] = lrelu(xlv[j] + xrv + ev) * attv;
      }
#pragma unroll
      for (int mk = 1; mk <= 16; mk <<= 1) {
#pragma unroll
        for (int j = 0; j < 4; j++) t[j] += __shfl_xor(t[j], mk, 64);
      }
#pragma unroll
      for (int j = 0; j < 4; j++) {
        float ex = exp2f(t[j]);
        ssum += ex;
        acc += ex * xlv[j];
      }
    }
    for (; p < s1; ++p) {
      int c0 = __builtin_amdgcn_readfirstlane(csr_src[p]);
      float xlv = b2f(xl[(unsigned)c0 * D + ch]);
      float ev;
      if constexpr (PRE) ev = b2f(ewp[(size_t)p * D + ch]);
      else ev = dot16u(pay + (size_t)p * 16, Wreg);
      float t = lrelu(xlv + xrv + ev) * attv;
#pragma unroll
      for (int mk = 1; mk <= 16; mk <<= 1) t += __shfl_xor(t, mk, 64);
      float ex = exp2f(t);
      ssum += ex;
      acc += ex * xlv;
    }
    agg[(size_t)node * D + ch] = f2b(acc / (ssum + 1e-16f));
  } else {
    int node = wid * NPW + lane / D;
    int s0 = start[node], s1 = start[node + 1];
    int deg = s1 - s0;
    int last = s1 - 1;
    int degmax = max(deg, __shfl_xor(deg, 32, 64));
    float xrv = b2f(xr[(unsigned)node * D + ch]);
    float ssum = 0.f, acc = 0.f;
    for (int i = 0; i < degmax; i += 8) {
      int pp[8];
      bool av[8];
      int cc[8];
#pragma unroll
      for (int j = 0; j < 8; j++) {
        pp[j] = min(s0 + i + j, last);
        av[j] = (i + j) < deg;
      }
#pragma unroll
      for (int j = 0; j < 8; j++) cc[j] = csr_src[pp[j]];
      float xlv[8];
#pragma unroll
      for (int j = 0; j < 8; j++) xlv[j] = b2f(xl[(unsigned)cc[j] * D + ch]);
      float t[8];
#pragma unroll
      for (int j = 0; j < 8; j++) {
        float ev;
        if constexpr (PRE) ev = b2f(ewp[(size_t)pp[j] * D + ch]);
        else ev = dot16b(pay + (size_t)pp[j] * 16, Wreg);
        t[j] = lrelu(xlv[j] + xrv + ev) * attv;
      }
#pragma unroll
      for (int mk = 1; mk <= 16; mk <<= 1) {
#pragma unroll
        for (int j = 0; j < 8; j++) t[j] += __shfl_xor(t[j], mk, 64);
      }
#pragma unroll
      for (int j = 0; j < 8; j++) {
        float ex = av[j] ? exp2f(t[j]) : 0.f;
        ssum += ex;
        acc += ex * xlv[j];
      }
    }
    agg[(size_t)node * D + ch] = f2b(acc / (ssum + 1e-16f));
  }
}

// ===== tier-2 eid-indirect fused =====
template <int H, int C>
__global__ __launch_bounds__(256) void k_fusedg(
    const int* __restrict__ start, const uint2* __restrict__ csr,
    const void* __restrict__ eattr, const int* __restrict__ flg,
    const float* __restrict__ mean_sums,
    const u16* __restrict__ xl, const u16* __restrict__ xr,
    const void* We, const void* att, u16* __restrict__ agg) {
  constexpr int D = H * C;
  constexpr int NPW = 64 / D;
  bool wb = flg[1] != 0;
  bool eb = flg[2] != 0;
  int lane = threadIdx.x & 63;
  int ch = lane % D;
  float Wreg[16];
  if (wb) {
    const u16* Wp = (const u16*)We;
#pragma unroll
    for (int k = 0; k < 16; k++) Wreg[k] = b2f(Wp[k * D + ch]);
  } else {
    const float* Wp = (const float*)We;
#pragma unroll
    for (int k = 0; k < 16; k++) Wreg[k] = Wp[k * D + ch];
  }
  float attv = wb ? b2f(((const u16*)att)[ch]) : ((const float*)att)[ch];
  float ev_self = 0.f;
#pragma unroll
  for (int k = 0; k < 16; k++) ev_self += mean_sums[k] * (1.0f / NE) * Wreg[k];
  int wid = (blockIdx.x * 256 + threadIdx.x) >> 6;
  int node = wid * NPW + lane / D;
  int s0 = start[node], s1 = start[node + 1];
  int deg = s1 - s0;
  int last = s1 - 1;
  int degmax = deg;
  if constexpr (NPW == 2) degmax = max(deg, __shfl_xor(deg, 32, 64));
  float xrv = b2f(xr[(size_t)node * D + ch]);
  float ssum = 0.f, acc = 0.f;
  for (int i = 0; i < degmax; i += 2) {
    uint2 cr0 = csr[min(s0 + i, last)];
    uint2 cr1 = csr[min(s0 + i + 1, last)];
    bool a0 = i < deg, a1 = i + 1 < deg;
    float xlv0 = b2f(xl[(size_t)cr0.x * D + ch]);
    float xlv1 = b2f(xl[(size_t)cr1.x * D + ch]);
    float ev0 = cr0.y < NE ? (eb ? dot16b((const u16*)eattr + (size_t)cr0.y * 16, Wreg)
                                 : dot16f((const float*)eattr + (size_t)cr0.y * 16, Wreg))
                           : ev_self;
    float ev1 = cr1.y < NE ? (eb ? dot16b((const u16*)eattr + (size_t)cr1.y * 16, Wreg)
                                 : dot16f((const float*)eattr + (size_t)cr1.y * 16, Wreg))
                           : ev_self;
    float mv0 = xlv0 + xrv + ev0;
    float mv1 = xlv1 + xrv + ev1;
    mv0 = (mv0 > 0.f) ? mv0 : 0.2f * mv0;
    mv1 = (mv1 > 0.f) ? mv1 : 0.2f * mv1;
    float t0 = mv0 * attv, t1 = mv1 * attv;
#pragma unroll
    for (int mk = 1; mk <= 16; mk <<= 1) {
      t0 += __shfl_xor(t0, mk, 64);
      t1 += __shfl_xor(t1, mk, 64);
    }
    float ex0 = a0 ? __expf(t0) : 0.f;
    float ex1 = a1 ? __expf(t1) : 0.f;
    ssum += ex0 + ex1;
    acc += ex0 * xlv0 + ex1 * xlv1;
  }
  agg[(size_t)node * D + ch] = f2b(acc / (ssum + 1e-16f));
}

// ========== batch-norm reduce ==========
template <int D>
__global__ __launch_bounds__(256) void k_bnred(const u16* __restrict__ v,
                                               float* __restrict__ sum,
                                               float* __restrict__ sq, int M) {
  constexpr int RB = 256 / D;
  int tid = threadIdx.x;
  int c = tid % D;
  int rg = tid / D;
  float s = 0.f, q = 0.f;
  for (int r = blockIdx.x * RB + rg; r < M; r += gridDim.x * RB) {
    float x = b2f(v[(size_t)r * D + c]);
    s += x;
    q += x * x;
  }
  __shared__ float ls[256], lq[256];
  ls[tid] = s; lq[tid] = q;
  __syncthreads();
  if (tid < D) {
    float ts = 0.f, tq = 0.f;
    for (int i = tid; i < 256; i += D) { ts += ls[i]; tq += lq[i]; }
    atomicAdd(&sum[tid], ts);
    atomicAdd(&sq[tid], tq);
  }
}

// ========== batch-norm apply + skip + ELU (layer 1) ==========
template <int D>
__global__ __launch_bounds__(256) void k_bnapply(const u16* __restrict__ agg,
                                                 const u16* __restrict__ hp,
                                                 const float* __restrict__ sum,
                                                 const float* __restrict__ sq,
                                                 const void* g, const void* b,
                                                 const int* __restrict__ flg,
                                                 u16* __restrict__ out, int M) {
  bool wb = flg[1] != 0;
  int idx = blockIdx.x * 256 + threadIdx.x;
  if (idx >= M * D) return;
  int c = idx & (D - 1);
  float gc = wb ? b2f(((const u16*)g)[c]) : ((const float*)g)[c];
  float bc = wb ? b2f(((const u16*)b)[c]) : ((const float*)b)[c];
  float mu = sum[c] * (1.f / M);
  float var = fmaxf(sq[c] * (1.f / M) - mu * mu, 0.f);
  float sc = rsqrtf(var + 1e-5f) * gc;
  float v = (b2f(agg[idx]) - mu) * sc + bc + b2f(hp[idx]);
  v = v > 0.f ? v : expm1f(v);
  out[idx] = f2b(v);
}

// ========== D11: BN2-apply + ELU + pool + (last block) finalize ==========
__global__ __launch_bounds__(256) void k_poolall(
    const u16* __restrict__ agg2, const u16* __restrict__ hp2,
    const float* __restrict__ sum, const float* __restrict__ sq,
    const void* g, const void* b, const int* __restrict__ flg,
    const int* __restrict__ batch,
    float* __restrict__ pool_sum, unsigned* __restrict__ pool_maxk,
    float* __restrict__ pool_cnt, int* __restrict__ done_cnt,
    void* __restrict__ out) {
  bool wb = flg[1] != 0;
  int c = threadIdx.x & 31;
  int rg = threadIdx.x >> 5;
  float gc = wb ? b2f(((const u16*)g)[c]) : ((const float*)g)[c];
  float bc = wb ? b2f(((const u16*)b)[c]) : ((const float*)b)[c];
  float mu = sum[c] * (1.f / NN);
  float var = fmaxf(sq[c] * (1.f / NN) - mu * mu, 0.f);
  float scl = rsqrtf(var + 1e-5f) * gc;
  float sh = bc - mu * scl;

  const int NPB = 256;
  int n0 = blockIdx.x * NPB;
  int nend = min(n0 + NPB, NN);
  int cur = -1;
  float s = 0.f, mx = 0.f;
  int cnt = 0;
  for (int n = n0 + rg; n < nend; n += 8) {
    int gi = batch[n];
    float v = b2f(agg2[(size_t)n * 32 + c]) * scl + sh + b2f(hp2[(size_t)n * 32 + c]);
    v = v > 0.f ? v : expm1f(v);
    if (gi != cur) {
      if (cur >= 0) {
        atomicAdd(&pool_sum[cur * 32 + c], s);
        atomicMax(&pool_maxk[cur * 32 + c], f2key(mx));
        if (c == 0) atomicAdd(&pool_cnt[cur], (float)cnt);
      }
      cur = gi; s = 0.f; mx = -INFINITY; cnt = 0;
    }
    s += v;
    mx = fmaxf(mx, v);
    cnt++;
  }
  if (cur >= 0) {
    atomicAdd(&pool_sum[cur * 32 + c], s);
    atomicMax(&pool_maxk[cur * 32 + c], f2key(mx));
    if (c == 0) atomicAdd(&pool_cnt[cur], (float)cnt);
  }
  __threadfence();
  __syncthreads();
  __shared__ int lastblk;
  if (threadIdx.x == 0) lastblk = (atomicAdd(done_cnt, 1) == (int)gridDim.x - 1);
  __syncthreads();
  if (!lastblk) return;
  bool ob = flg[3] != 0;
  for (int idx = threadIdx.x; idx < NG * 64; idx += 256) {
    int gi = idx / 64, cc = idx % 64;
    float cntv = atomicAdd(&pool_cnt[gi], 0.f);
    float val;
    if (cc < 32) val = atomicAdd(&pool_sum[gi * 32 + cc], 0.f) / fmaxf(cntv, 1.f);
    else {
      unsigned k = atomicMax(&pool_maxk[gi * 32 + (cc - 32)], 0u);
      val = cntv > 0.f ? key2f(k) : 0.f;
    }
    if (ob) ((u16*)out)[idx] = f2b(val);
    else ((float*)out)[idx] = val;
  }
}

extern "C" void kernel_launch(void* const* d_in, const int* in_sizes, int n_in,
                              void* d_out, int out_size, void* d_ws, size_t ws_size,
                              hipStream_t stream) {
  (void)in_sizes; (void)n_in; (void)out_size;
  const void* x     = d_in[0];
  const int*  ei    = (const int*)d_in[1];
  const void* eattr = d_in[2];
  const int*  batch = (const int*)d_in[3];
  const void* skip1_W = d_in[4];
  const void* skip1_b = d_in[5];
  const void* c1_Wl = d_in[6];
  const void* c1_bl = d_in[7];
  const void* c1_Wr = d_in[8];
  const void* c1_br = d_in[9];
  const void* c1_We = d_in[10];
  const void* c1_att = d_in[11];
  const void* bn1_g = d_in[13];
  const void* bn1_b = d_in[14];
  const void* skip2_W = d_in[15];
  const void* skip2_b = d_in[16];
  const void* c2_Wl = d_in[17];
  const void* c2_bl = d_in[18];
  const void* c2_Wr = d_in[19];
  const void* c2_br = d_in[20];
  const void* c2_We = d_in[21];
  const void* c2_att = d_in[22];
  const void* bn2_g = d_in[24];
  const void* bn2_b = d_in[25];

  float* ws = (float*)d_ws;
  size_t off = 0;
  auto alloc = [&](size_t nfl) {
    float* p = ws + off;
    off += (nfl + 15) & ~(size_t)15;
    return p;
  };
  // ---- zero-initialized region ----
  int*   flags      = (int*)alloc(16);
  float* mean_sums  = alloc(16);
  float* mean_part  = alloc(64 * 16);
  int*   deg8       = (int*)alloc((size_t)NDEG * NN);
  float* bnsum1     = alloc(64);
  float* bnsq1      = alloc(64);
  float* bnsum2     = alloc(32);
  float* bnsq2      = alloc(32);
  float* pool_cnt   = alloc(NG);
  float* pool_sum   = alloc(NG * 32);
  unsigned* pool_maxk = (unsigned*)alloc(NG * 32);
  int*   done_pool  = (int*)alloc(16);
  size_t zcnt16 = (off * sizeof(float)) / 16;
  // ---- common (not zeroed) ----
  int*   tile_tot = (int*)alloc(64);
  u16* xh  = (u16*)alloc((size_t)NN * 64);
  u16* xlo = (u16*)alloc((size_t)NN * 64);
  size_t zoff = off;

  // ---- tier 0: CSR payload + precomputed EW (~233 MB) ----
  int* start   = (int*)alloc(NN + 1);
  int* cursor  = (int*)alloc(NN);
  int* csr_src = (int*)alloc(ETOT);
  u16* ea16    = (u16*)alloc((size_t)ETOT * 8);
  u16* ew1     = (u16*)alloc((size_t)ETOT * 32);  // [ETOT][64] bf16
  u16* ew2     = (u16*)alloc((size_t)ETOT * 16);  // [ETOT][32] bf16
  uint2* csr = nullptr;
  u16* xl1 = (u16*)alloc((size_t)NN * 32);
  u16* xr1 = (u16*)alloc((size_t)NN * 32);
  u16* hp1 = (u16*)alloc((size_t)NN * 32);
  u16* agg = (u16*)alloc((size_t)NN * 32);
  int tier = 0;
  if (off * sizeof(float) > ws_size) {
    tier = 1;
    off = zoff;
    start   = (int*)alloc(NN + 1);
    cursor  = (int*)alloc(NN);
    csr_src = (int*)alloc(ETOT);
    ea16    = (u16*)alloc((size_t)ETOT * 8);
    ew1 = ew2 = nullptr;
    xl1 = (u16*)alloc((size_t)NN * 32);
    xr1 = (u16*)alloc((size_t)NN * 32);
    hp1 = (u16*)alloc((size_t)NN * 32);
    agg = (u16*)alloc((size_t)NN * 32);
  }
  if (tier == 1 && off * sizeof(float) > ws_size) {
    tier = 2;
    off = zoff;
    start   = (int*)alloc(NN + 1);
    cursor  = (int*)alloc(NN);
    csr     = (uint2*)alloc((size_t)ETOT * 2);
    ea16    = nullptr;
    xl1 = (u16*)alloc((size_t)NN * 32);
    xr1 = (u16*)alloc((size_t)NN * 32);
    hp1 = (u16*)alloc((size_t)NN * 32);
    agg = (u16*)alloc((size_t)NN * 32);
  }
  u16* h1  = xr1;
  u16* xl2 = xl1;
  u16* xr2 = xl1 + (size_t)NN * 32;
  u16* hp2 = hp1;

  int eg = (ETOT + 255) / 256;

  // D1: zero + detect
  k_init<<<128, 256, 0, stream>>>((uint4*)d_ws, (int)zcnt16,
                                  (const unsigned*)x, (const unsigned*)skip1_W,
                                  (const unsigned*)eattr, flags);
  // D2a: deg scatter (tiny waves, pure TLP)
  k_hist<<<eg, 256, 0, stream>>>(ei, deg8);
  // D2: colsum + x split (pure streaming)
  k_colsum_xsplit<<<2048, 256, 0, stream>>>(eattr, x, flags, mean_part, xh, xlo);
  // D2b: per-tile degree sums (parallel)
  k_scansum<<<SCAN_NT, 256, 0, stream>>>(deg8, mean_part, mean_sums, tile_tot);
  // D2c: prefix + write start/cursor (parallel)
  k_scanwrite<<<SCAN_NT, 256, 0, stream>>>(deg8, tile_tot, start, cursor);
  // D3: lin3 L1 (pure GEMM)
  k_lin1<128, 64, 625, 5><<<1875, 256, 0, stream>>>(
      x, xh, xlo, flags, c1_Wl, c1_Wr, skip1_W,
      c1_bl, c1_br, skip1_b, xl1, xr1, hp1);
  // D4: CSR build
  if (tier <= 1) {
    k_buildcsr_pay<<<eg, 256, 0, stream>>>(ei, eattr, flags, mean_sums,
                                           cursor, csr_src, ea16);
  } else {
    k_buildcsr<<<eg, 256, 0, stream>>>(ei, cursor, csr);
  }
  // D4c: EW precompute GEMM (tier 0 only)
  if (tier == 0) {
    k_ewgemm<<<1024, 256, 0, stream>>>(ea16, flags, c1_We, c2_We, ew1, ew2);
  }
  // D5: fused L1
  if (tier == 0) {
    k_fusedp<2, 32, true><<<NN / 4, 256, 0, stream>>>(start, csr_src, ea16, ew1,
                                                      flags, xl1, xr1, c1_We,
                                                      c1_att, agg);
  } else if (tier == 1) {
    k_fusedp<2, 32, false><<<NN / 4, 256, 0, stream>>>(start, csr_src, ea16, nullptr,
                                                       flags, xl1, xr1, c1_We,
                                                       c1_att, agg);
  } else {
    k_fusedg<2, 32><<<NN / 4, 256, 0, stream>>>(start, csr, eattr, flags, mean_sums,
                                                xl1, xr1, c1_We, c1_att, agg);
  }
  // D6: bnred L1
  k_bnred<64><<<256, 256, 0, stream>>>(agg, bnsum1, bnsq1, NN);
  // D7: bn apply L1
  k_bnapply<64><<<(NN * 64 + 255) / 256, 256, 0, stream>>>(agg, hp1, bnsum1, bnsq1,
                                                           bn1_g, bn1_b, flags, h1, NN);
  // D8: lin3 L2 (LDS-free MFMA)
  {
    dim3 g(625, 3);
    k_lin3b<64, 32, 5><<<g, 256, 0, stream>>>(h1, flags, c2_Wl, c2_Wr, skip2_W,
                                              c2_bl, c2_br, skip2_b,
                                              xl2, xr2, hp2, NN);
  }
  // D9: fused L2
  if (tier == 0) {
    k_fusedp<1, 32, true><<<NN / 8, 256, 0, stream>>>(start, csr_src, ea16, ew2,
                                                      flags, xl2, xr2, c2_We,
                                                      c2_att, agg);
  } else if (tier == 1) {
    k_fusedp<1, 32, false><<<NN / 8, 256, 0, stream>>>(start, csr_src, ea16, nullptr,
                                                       flags, xl2, xr2, c2_We,
                                                       c2_att, agg);
  } else {
    k_fusedg<1, 32><<<NN / 8, 256, 0, stream>>>(start, csr, eattr, flags, mean_sums,
                                                xl2, xr2, c2_We, c2_att, agg);
  }
  // D10: bnred L2
  k_bnred<32><<<256, 256, 0, stream>>>(agg, bnsum2, bnsq2, NN);
  // D11: bn2 apply + pool + finalize
  k_poolall<<<(NN + 255) / 256, 256, 0, stream>>>(agg, hp2, bnsum2, bnsq2,
                                                  bn2_g, bn2_b, flags, batch,
                                                  pool_sum, pool_maxk, pool_cnt,
                                                  done_pool, d_out);
}

// Round 11
// 515.494 us; speedup vs baseline: 1.0762x; 1.0762x over previous
//
#include <hip/hip_runtime.h>
#include <hip/hip_bf16.h>

#define NE 800000
#define NN 50000
#define NG 16
#define ETOT (NE + NN)

typedef unsigned short u16;
typedef __attribute__((ext_vector_type(8))) short short8;
typedef __attribute__((ext_vector_type(4))) float float4v;

__device__ __forceinline__ float b2f(u16 u) {
  return __uint_as_float(((unsigned)u) << 16);
}
__device__ __forceinline__ u16 f2b(float f) {
  __hip_bfloat16 b = __float2bfloat16(f);
  return *(u16*)&b;
}
__device__ __forceinline__ void cv8(uint4 v, float* o) {
  o[0] = __uint_as_float(v.x << 16);
  o[1] = __uint_as_float(v.x & 0xFFFF0000u);
  o[2] = __uint_as_float(v.y << 16);
  o[3] = __uint_as_float(v.y & 0xFFFF0000u);
  o[4] = __uint_as_float(v.z << 16);
  o[5] = __uint_as_float(v.z & 0xFFFF0000u);
  o[6] = __uint_as_float(v.w << 16);
  o[7] = __uint_as_float(v.w & 0xFFFF0000u);
}
__device__ __forceinline__ unsigned pk2(float a, float b) {
  return (unsigned)f2b(a) | ((unsigned)f2b(b) << 16);
}
__device__ __forceinline__ unsigned f2key(float f) {
  unsigned u = __float_as_uint(f);
  return (u & 0x80000000u) ? ~u : (u | 0x80000000u);
}
__device__ __forceinline__ float key2f(unsigned k) {
  unsigned u = (k & 0x80000000u) ? (k ^ 0x80000000u) : ~k;
  return __uint_as_float(u);
}
__device__ __forceinline__ int plaus(unsigned h) {
  unsigned eh = (h >> 7) & 0xFF;
  return (h == 0) || (eh >= 100 && eh <= 140);
}
__device__ __forceinline__ float lrelu(float v) {
  return (v > 0.f) ? v : 0.2f * v;
}

#define NDEG 8   // deg privatization copies
#define NPOOL 16 // pool privatization copies
#define LOG2E 1.4426950408889634f

// ========== D1: zero accumulator region + dtype detect (block 0; NO fence) ==========
__global__ __launch_bounds__(256) void k_init(uint4* __restrict__ zbase, int zcnt16,
                                              const unsigned* __restrict__ a,
                                              const unsigned* __restrict__ b,
                                              const unsigned* __restrict__ c,
                                              int* __restrict__ flags) {
  uint4 z = {0, 0, 0, 0};
  for (int i = blockIdx.x * 256 + threadIdx.x; i < zcnt16; i += gridDim.x * 256)
    zbase[i] = z;
  if (blockIdx.x != 0) return;
  __shared__ int cnt[3];
  if (threadIdx.x < 3) cnt[threadIdx.x] = 0;
  __syncthreads();
  const unsigned* arr[3] = {a, b, c};
  for (int k = 0; k < 3; k++) {
    int ok = 0;
    for (int i = threadIdx.x; i < 4096; i += 256) {
      unsigned w = arr[k][i];
      ok += (plaus(w & 0xFFFFu) && plaus(w >> 16)) ? 1 : 0;
    }
    atomicAdd(&cnt[k], ok);
  }
  __syncthreads();
  if (threadIdx.x == 0) {
    int f0 = cnt[0] > 2048, f1 = cnt[1] > 2048, f2 = cnt[2] > 2048;
    flags[0] = f0;
    flags[1] = f1;
    flags[2] = f2;
    flags[3] = f0 && f1 && f2;
  }
}

// ========== D2a: deg scatter ONLY (8-way privatized) ==========
__global__ __launch_bounds__(256) void k_hist(const int* __restrict__ ei,
                                              int* __restrict__ deg8) {
  int gt = blockIdx.x * 256 + threadIdx.x;
  if (gt >= ETOT) return;
  int dst = (gt < NE) ? ei[NE + gt] : gt - NE;
  atomicAdd(&deg8[(blockIdx.x & (NDEG - 1)) * NN + dst], 1);
}

// ========== D2: edge_attr colsums + x hi/lo bf16 split (pure streaming) ==========
__global__ __launch_bounds__(256) void k_colsum_xsplit(
    const void* __restrict__ ea, const void* __restrict__ xin,
    const int* __restrict__ flg, float* __restrict__ mean_part,
    u16* __restrict__ xh, u16* __restrict__ xlo) {
  int gt = blockIdx.x * 256 + threadIdx.x;
  bool eb = flg[2] != 0;
  int col = gt & 15;
  int row = gt >> 4;
  int rstride = (gridDim.x * 256) >> 4;
  float s = 0.f;
  if (eb) {
    const u16* p = (const u16*)ea;
    for (int e = row; e < NE; e += rstride) s += b2f(p[(size_t)e * 16 + col]);
  } else {
    const float* p = (const float*)ea;
    for (int e = row; e < NE; e += rstride) s += p[(size_t)e * 16 + col];
  }
  __shared__ float ls[256];
  ls[threadIdx.x] = s;
  __syncthreads();
  if (threadIdx.x < 16) {
    float t = 0.f;
    for (int i = threadIdx.x; i < 256; i += 16) t += ls[i];
    atomicAdd(&mean_part[(blockIdx.x & 63) * 16 + threadIdx.x], t);
  }
  if (flg[0] == 0) {
    const float4* xp4 = (const float4*)xin;
    const int nch = NN * 32;
    int stride = gridDim.x * 256;
    for (int i = gt; i < nch; i += stride) {
      float4 v = xp4[i];
      u16 h0 = f2b(v.x), h1 = f2b(v.y), h2 = f2b(v.z), h3 = f2b(v.w);
      u16 l0 = f2b(v.x - b2f(h0));
      u16 l1 = f2b(v.y - b2f(h1));
      u16 l2 = f2b(v.z - b2f(h2));
      u16 l3 = f2b(v.w - b2f(h3));
      uint2 ho, lo2;
      ho.x = (unsigned)h0 | ((unsigned)h1 << 16);
      ho.y = (unsigned)h2 | ((unsigned)h3 << 16);
      lo2.x = (unsigned)l0 | ((unsigned)l1 << 16);
      lo2.y = (unsigned)l2 | ((unsigned)l3 << 16);
      *(uint2*)(xh + (size_t)i * 4) = ho;
      *(uint2*)(xlo + (size_t)i * 4) = lo2;
    }
  }
}

#define SCAN_NT ((NN + 1023) / 1024)  // 49

// ========== D2b: per-tile degree sums (49 blocks) ==========
__global__ __launch_bounds__(256) void k_scansum(const int* __restrict__ deg8,
                                                 const float* __restrict__ mean_part,
                                                 float* __restrict__ mean_sums,
                                                 int* __restrict__ tile_tot) {
  int t = threadIdx.x;
  if (blockIdx.x == 0 && t < 16) {
    float s = 0.f;
#pragma unroll
    for (int j = 0; j < 64; j++) s += mean_part[j * 16 + t];
    mean_sums[t] = s;
  }
  int lane = t & 63;
  int wv = t >> 6;
  int idx = blockIdx.x * 1024 + t * 4;
  int s4 = 0;
  if (idx + 3 < NN) {
#pragma unroll
    for (int c = 0; c < NDEG; c++) {
      int4 dc = *(const int4*)(deg8 + c * NN + idx);
      s4 += dc.x + dc.y + dc.z + dc.w;
    }
  } else {
#pragma unroll
    for (int c = 0; c < NDEG; c++) {
      if (idx + 0 < NN) s4 += deg8[c * NN + idx + 0];
      if (idx + 1 < NN) s4 += deg8[c * NN + idx + 1];
      if (idx + 2 < NN) s4 += deg8[c * NN + idx + 2];
      if (idx + 3 < NN) s4 += deg8[c * NN + idx + 3];
    }
  }
  int r = s4;
#pragma unroll
  for (int ofs = 1; ofs < 64; ofs <<= 1) r += __shfl_xor(r, ofs, 64);
  __shared__ int wsum[4];
  if (lane == 0) wsum[wv] = r;
  __syncthreads();
  if (t == 0) tile_tot[blockIdx.x] = wsum[0] + wsum[1] + wsum[2] + wsum[3];
}

// ========== D2c: prefix bases + per-tile scan + start/cursor write (49 blocks) ==========
__global__ __launch_bounds__(256) void k_scanwrite(const int* __restrict__ deg8,
                                                   const int* __restrict__ tile_tot,
                                                   int* __restrict__ start,
                                                   int* __restrict__ cursor) {
  __shared__ int sbase;
  __shared__ int wsum[4];
  int t = threadIdx.x;
  int lane = t & 63;
  int wv = t >> 6;
  if (wv == 0) {
    int v = (lane < SCAN_NT) ? tile_tot[lane] : 0;
    int sc = v;
#pragma unroll
    for (int ofs = 1; ofs < 64; ofs <<= 1) {
      int u = __shfl_up(sc, ofs, 64);
      if (lane >= ofs) sc += u;
    }
    if (lane == (int)blockIdx.x) sbase = sc - v;
    if (blockIdx.x == 0 && lane == SCAN_NT - 1) start[NN] = sc;
  }
  int idx = blockIdx.x * 1024 + t * 4;
  int4 d = {0, 0, 0, 0};
  if (idx + 3 < NN) {
#pragma unroll
    for (int c = 0; c < NDEG; c++) {
      int4 dc = *(const int4*)(deg8 + c * NN + idx);
      d.x += dc.x; d.y += dc.y; d.z += dc.z; d.w += dc.w;
    }
  } else {
#pragma unroll
    for (int c = 0; c < NDEG; c++) {
      if (idx + 0 < NN) d.x += deg8[c * NN + idx + 0];
      if (idx + 1 < NN) d.y += deg8[c * NN + idx + 1];
      if (idx + 2 < NN) d.z += deg8[c * NN + idx + 2];
      if (idx + 3 < NN) d.w += deg8[c * NN + idx + 3];
    }
  }
  int s4 = d.x + d.y + d.z + d.w;
  int sc = s4;
#pragma unroll
  for (int ofs = 1; ofs < 64; ofs <<= 1) {
    int v = __shfl_up(sc, ofs, 64);
    if (lane >= ofs) sc += v;
  }
  if (lane == 63) wsum[wv] = sc;
  __syncthreads();
  int wbase = 0;
#pragma unroll
  for (int w = 0; w < 4; w++)
    if (w < wv) wbase += wsum[w];
  int excl = sbase + wbase + (sc - s4);
  int4 st;
  st.x = excl;
  st.y = excl + d.x;
  st.z = st.y + d.y;
  st.w = st.z + d.z;
  if (idx + 3 < NN) {
    *(int4*)(start + idx) = st;
    *(int4*)(cursor + idx) = st;
  } else {
    if (idx + 0 < NN) { start[idx + 0] = st.x; cursor[idx + 0] = st.x; }
    if (idx + 1 < NN) { start[idx + 1] = st.y; cursor[idx + 1] = st.y; }
    if (idx + 2 < NN) { start[idx + 2] = st.z; cursor[idx + 2] = st.z; }
    if (idx + 3 < NN) { start[idx + 3] = st.w; cursor[idx + 3] = st.w; }
  }
}

// ===== LDS-free split-bf16 MFMA GEMM tile =====
template <int K, int N, int RPB>
__device__ __forceinline__ void gemm_direct(
    const void* __restrict__ W, const void* __restrict__ bb, bool wb,
    const u16* __restrict__ xh, const u16* __restrict__ xlo, bool has_lo,
    u16* __restrict__ out, int tile) {
  constexpr int CT = N / 16;
  constexpr int WPC = 4 / CT;
  constexpr int KK = K / 32;
  int lane = threadIdx.x & 63;
  int wave = threadIdx.x >> 6;
  int col = lane & 15;
  int quad = lane >> 4;
  int ct = wave % CT;
  int rt_off = wave / CT;
  short8 bh[KK], bl[KK];
#pragma unroll
  for (int kk = 0; kk < KK; kk++) {
    short8 th, tl;
#pragma unroll
    for (int j = 0; j < 8; j++) {
      int k = kk * 32 + quad * 8 + j;
      float w = wb ? b2f(((const u16*)W)[k * N + ct * 16 + col])
                   : ((const float*)W)[k * N + ct * 16 + col];
      u16 hb = f2b(w);
      th[j] = (short)hb;
      tl[j] = (short)f2b(w - b2f(hb));
    }
    bh[kk] = th;
    bl[kk] = tl;
  }
  float bias = wb ? b2f(((const u16*)bb)[ct * 16 + col])
                  : ((const float*)bb)[ct * 16 + col];
  int rt0 = tile * RPB;
  for (int i = rt_off; i < RPB; i += WPC) {
    int rt = rt0 + i;
    int row = rt * 16 + col;
    float4v acc = {0.f, 0.f, 0.f, 0.f};
#pragma unroll
    for (int kk = 0; kk < KK; kk++) {
      short8 afh = *(const short8*)(xh + (size_t)row * K + kk * 32 + quad * 8);
      acc = __builtin_amdgcn_mfma_f32_16x16x32_bf16(afh, bh[kk], acc, 0, 0, 0);
      if (has_lo) {
        short8 afl = *(const short8*)(xlo + (size_t)row * K + kk * 32 + quad * 8);
        acc = __builtin_amdgcn_mfma_f32_16x16x32_bf16(afl, bh[kk], acc, 0, 0, 0);
      }
      if (!wb)
        acc = __builtin_amdgcn_mfma_f32_16x16x32_bf16(afh, bl[kk], acc, 0, 0, 0);
    }
#pragma unroll
    for (int r = 0; r < 4; r++) {
      int orow = rt * 16 + quad * 4 + r;
      out[(size_t)orow * N + ct * 16 + col] = f2b(acc[r] + bias);
    }
  }
}

// ========== D3: lin3 L1 (pure GEMM) ==========
template <int K, int N, int TILES, int RPB>
__global__ __launch_bounds__(256) void k_lin1(
    const void* __restrict__ xin, const u16* __restrict__ xh,
    const u16* __restrict__ xlo, const int* __restrict__ flg,
    const void* W0, const void* W1, const void* W2,
    const void* b0, const void* b1, const void* b2,
    u16* __restrict__ o0, u16* __restrict__ o1, u16* __restrict__ o2) {
  int lidx = blockIdx.x;
  int wset = lidx / TILES;
  int tile = lidx % TILES;
  bool wb = flg[1] != 0;
  bool xb = flg[0] != 0;
  const void* W = wset == 0 ? W0 : (wset == 1 ? W1 : W2);
  const void* bb = wset == 0 ? b0 : (wset == 1 ? b1 : b2);
  u16* out = wset == 0 ? o0 : (wset == 1 ? o1 : o2);
  const u16* ah = xb ? (const u16*)xin : xh;
  gemm_direct<K, N, RPB>(W, bb, wb, ah, xlo, !xb, out, tile);
}

// ========== D4: CSR build ==========
__global__ __launch_bounds__(256) void k_buildcsr_pay(
    const int* __restrict__ ei, const void* __restrict__ eattr,
    const int* __restrict__ flg, const float* __restrict__ mean_sums,
    int* __restrict__ cursor, int* __restrict__ csr_src,
    u16* __restrict__ ea16) {
  int e = blockIdx.x * 256 + threadIdx.x;
  if (e >= ETOT) return;
  bool eb = flg[2] != 0;
  int src, dst;
  if (e < NE) { src = ei[e]; dst = ei[NE + e]; } else { src = dst = e - NE; }
  float rec[16];
  if (e < NE) {
    if (eb) {
      const uint4* q = (const uint4*)((const u16*)eattr + (size_t)e * 16);
      cv8(q[0], rec);
      cv8(q[1], rec + 8);
    } else {
      const float* q = (const float*)eattr + (size_t)e * 16;
#pragma unroll
      for (int k = 0; k < 16; k++) rec[k] = q[k];
    }
  } else {
#pragma unroll
    for (int k = 0; k < 16; k++) rec[k] = mean_sums[k] * (1.0f / NE);
  }
  int pos = atomicAdd(&cursor[dst], 1);
  csr_src[pos] = src;
  u16 rb[16];
#pragma unroll
  for (int k = 0; k < 16; k++) rb[k] = f2b(rec[k]);
  uint4* dp = (uint4*)(ea16 + (size_t)pos * 16);
  dp[0] = *(uint4*)rb;
  dp[1] = *(uint4*)(rb + 8);
}

__global__ __launch_bounds__(256) void k_buildcsr(const int* __restrict__ ei,
                                                  int* __restrict__ cursor,
                                                  uint2* __restrict__ csr) {
  int e = blockIdx.x * 256 + threadIdx.x;
  if (e >= ETOT) return;
  int src, dst;
  if (e < NE) { src = ei[e]; dst = ei[NE + e]; } else { src = dst = e - NE; }
  int pos = atomicAdd(&cursor[dst], 1);
  uint2 r; r.x = (unsigned)src; r.y = (unsigned)e;
  csr[pos] = r;
}

// ========== D4c: EW = payload @ We GEMM (tier0 only) ==========
__global__ __launch_bounds__(256) void k_ewgemm(
    const u16* __restrict__ ea, const int* __restrict__ flg,
    const void* We1, const void* We2,
    u16* __restrict__ ew1, u16* __restrict__ ew2) {
  bool wb = flg[1] != 0;
  int lane = threadIdx.x & 63;
  int col = lane & 15;
  int quad = lane >> 4;
  short8 b1h[4], b1l[4], b2h[2], b2l[2];
#pragma unroll
  for (int ct = 0; ct < 4; ct++) {
    short8 th, tl;
#pragma unroll
    for (int j = 0; j < 8; j++) {
      int k = quad * 8 + j;
      float w = 0.f;
      if (k < 16)
        w = wb ? b2f(((const u16*)We1)[k * 64 + ct * 16 + col])
               : ((const float*)We1)[k * 64 + ct * 16 + col];
      u16 hb = f2b(w);
      th[j] = (short)hb;
      tl[j] = (short)f2b(w - b2f(hb));
    }
    b1h[ct] = th; b1l[ct] = tl;
  }
#pragma unroll
  for (int ct = 0; ct < 2; ct++) {
    short8 th, tl;
#pragma unroll
    for (int j = 0; j < 8; j++) {
      int k = quad * 8 + j;
      float w = 0.f;
      if (k < 16)
        w = wb ? b2f(((const u16*)We2)[k * 32 + ct * 16 + col])
               : ((const float*)We2)[k * 32 + ct * 16 + col];
      u16 hb = f2b(w);
      th[j] = (short)hb;
      tl[j] = (short)f2b(w - b2f(hb));
    }
    b2h[ct] = th; b2l[ct] = tl;
  }
  int nw = (gridDim.x * 256) >> 6;
  int wid = (blockIdx.x * 256 + threadIdx.x) >> 6;
  const int NT = ETOT / 16;  // 53125 exact
  for (int rt = wid; rt < NT; rt += nw) {
    int row = rt * 16 + col;
    short8 af = {0, 0, 0, 0, 0, 0, 0, 0};
    if (quad < 2) af = *(const short8*)(ea + (size_t)row * 16 + quad * 8);
#pragma unroll
    for (int ct = 0; ct < 4; ct++) {
      float4v acc = {0.f, 0.f, 0.f, 0.f};
      acc = __builtin_amdgcn_mfma_f32_16x16x32_bf16(af, b1h[ct], acc, 0, 0, 0);
      acc = __builtin_amdgcn_mfma_f32_16x16x32_bf16(af, b1l[ct], acc, 0, 0, 0);
#pragma unroll
      for (int r = 0; r < 4; r++)
        ew1[(size_t)(rt * 16 + quad * 4 + r) * 64 + ct * 16 + col] = f2b(acc[r]);
    }
#pragma unroll
    for (int ct = 0; ct < 2; ct++) {
      float4v acc = {0.f, 0.f, 0.f, 0.f};
      acc = __builtin_amdgcn_mfma_f32_16x16x32_bf16(af, b2h[ct], acc, 0, 0, 0);
      acc = __builtin_amdgcn_mfma_f32_16x16x32_bf16(af, b2l[ct], acc, 0, 0, 0);
#pragma unroll
      for (int r = 0; r < 4; r++)
        ew2[(size_t)(rt * 16 + quad * 4 + r) * 32 + ct * 16 + col] = f2b(acc[r]);
    }
  }
}

// ==== standalone lin3 (layer 2) — LDS-free; xin (h1) always bf16 ====
template <int K, int N, int RPB>
__global__ __launch_bounds__(256) void k_lin3b(
    const void* __restrict__ xin, const int* __restrict__ flg,
    const void* W0, const void* W1, const void* W2,
    const void* b0, const void* b1, const void* b2,
    u16* __restrict__ o0, u16* __restrict__ o1, u16* __restrict__ o2, int M) {
  (void)M;
  bool wb = flg[1] != 0;
  const void* W = blockIdx.y == 0 ? W0 : (blockIdx.y == 1 ? W1 : W2);
  const void* bb = blockIdx.y == 0 ? b0 : (blockIdx.y == 1 ? b1 : b2);
  u16* out = blockIdx.y == 0 ? o0 : (blockIdx.y == 1 ? o1 : o2);
  gemm_direct<K, N, RPB>(W, bb, wb, (const u16*)xin, nullptr, false, out,
                         blockIdx.x);
}

// ===== payload dots =====
__device__ __forceinline__ float dot16b(const u16* __restrict__ p,
                                        const float* __restrict__ W) {
  float ea[16];
  const uint4* q = (const uint4*)p;
  cv8(q[0], ea);
  cv8(q[1], ea + 8);
  float s = 0.f;
#pragma unroll
  for (int k = 0; k < 16; k++) s += ea[k] * W[k];
  return s;
}
__device__ __forceinline__ float dot16u(const u16* __restrict__ p,
                                        const float* __restrict__ W) {
  const uint4* q = (const uint4*)p;
  uint4 A = q[0], B = q[1];
  unsigned w0 = (unsigned)__builtin_amdgcn_readfirstlane((int)A.x);
  unsigned w1 = (unsigned)__builtin_amdgcn_readfirstlane((int)A.y);
  unsigned w2 = (unsigned)__builtin_amdgcn_readfirstlane((int)A.z);
  unsigned w3 = (unsigned)__builtin_amdgcn_readfirstlane((int)A.w);
  unsigned w4 = (unsigned)__builtin_amdgcn_readfirstlane((int)B.x);
  unsigned w5 = (unsigned)__builtin_amdgcn_readfirstlane((int)B.y);
  unsigned w6 = (unsigned)__builtin_amdgcn_readfirstlane((int)B.z);
  unsigned w7 = (unsigned)__builtin_amdgcn_readfirstlane((int)B.w);
  float s = 0.f;
  s += __uint_as_float(w0 << 16) * W[0];
  s += __uint_as_float(w0 & 0xFFFF0000u) * W[1];
  s += __uint_as_float(w1 << 16) * W[2];
  s += __uint_as_float(w1 & 0xFFFF0000u) * W[3];
  s += __uint_as_float(w2 << 16) * W[4];
  s += __uint_as_float(w2 & 0xFFFF0000u) * W[5];
  s += __uint_as_float(w3 << 16) * W[6];
  s += __uint_as_float(w3 & 0xFFFF0000u) * W[7];
  s += __uint_as_float(w4 << 16) * W[8];
  s += __uint_as_float(w4 & 0xFFFF0000u) * W[9];
  s += __uint_as_float(w5 << 16) * W[10];
  s += __uint_as_float(w5 & 0xFFFF0000u) * W[11];
  s += __uint_as_float(w6 << 16) * W[12];
  s += __uint_as_float(w6 & 0xFFFF0000u) * W[13];
  s += __uint_as_float(w7 << 16) * W[14];
  s += __uint_as_float(w7 & 0xFFFF0000u) * W[15];
  return s;
}
__device__ __forceinline__ float dot16f(const float* __restrict__ q,
                                        const float* __restrict__ W) {
  float s = 0.f;
#pragma unroll
  for (int k = 0; k < 16; k++) s += q[k] * W[k];
  return s;
}

// ===== D5/D9: fused attention + softmax gather-reduce (8-edge ILP, exp2) =====
template <int H, int C, bool PRE>
__global__ __launch_bounds__(256) void k_fusedp(
    const int* __restrict__ start, const int* __restrict__ csr_src,
    const u16* __restrict__ pay, const u16* __restrict__ ewp,
    const int* __restrict__ flg,
    const u16* __restrict__ xl, const u16* __restrict__ xr,
    const void* We, const void* att, u16* __restrict__ agg) {
  constexpr int D = H * C;
  constexpr int NPW = 64 / D;
  bool wb = flg[1] != 0;
  int lane = threadIdx.x & 63;
  int ch = lane % D;
  float Wreg[16];
  if constexpr (!PRE) {
    if (wb) {
      const u16* Wp = (const u16*)We;
#pragma unroll
      for (int k = 0; k < 16; k++) Wreg[k] = b2f(Wp[k * D + ch]);
    } else {
      const float* Wp = (const float*)We;
#pragma unroll
      for (int k = 0; k < 16; k++) Wreg[k] = Wp[k * D + ch];
    }
  }
  float attv = (wb ? b2f(((const u16*)att)[ch]) : ((const float*)att)[ch]) * LOG2E;
  int wid = (blockIdx.x * 256 + threadIdx.x) >> 6;

  if constexpr (NPW == 1) {
    int node = __builtin_amdgcn_readfirstlane(wid);
    int s0 = __builtin_amdgcn_readfirstlane(start[node]);
    int s1 = __builtin_amdgcn_readfirstlane(start[node + 1]);
    float xrv = b2f(xr[(unsigned)node * D + ch]);
    float ssum = 0.f, acc = 0.f;
    int p = s0;
    for (; p + 7 < s1; p += 8) {
      int c[8];
#pragma unroll
      for (int j = 0; j < 8; j++)
        c[j] = __builtin_amdgcn_readfirstlane(csr_src[p + j]);
      float xlv[8];
#pragma unroll
      for (int j = 0; j < 8; j++) xlv[j] = b2f(xl[(unsigned)c[j] * D + ch]);
      float t[8];
#pragma unroll
      for (int j = 0; j < 8; j++) {
        float ev;
        if constexpr (PRE) ev = b2f(ewp[(size_t)(p + j) * D + ch]);
        else ev = dot16u(pay + (size_t)(p + j) * 16, Wreg);
        t[j] = lrelu(xlv[j] + xrv + ev) * attv;
      }
#pragma unroll
      for (int mk = 1; mk <= 16; mk <<= 1) {
#pragma unroll
        for (int j = 0; j < 8; j++) t[j] += __shfl_xor(t[j], mk, 64);
      }
#pragma unroll
      for (int j = 0; j < 8; j++) {
        float ex = exp2f(t[j]);
        ssum += ex;
        acc += ex * xlv[j];
      }
    }
    for (; p + 3 < s1; p += 4) {
      int c[4];
#pragma unroll
      for (int j = 0; j < 4; j++)
        c[j] = __builtin_amdgcn_readfirstlane(csr_src[p + j]);
      float xlv[4], t[4];
#pragma unroll
      for (int j = 0; j < 4; j++) xlv[j] = b2f(xl[(unsigned)c[j] * D + ch]);
#pragma unroll
      for (int j = 0; j < 4; j++) {
        float ev;
        if constexpr (PRE) ev = b2f(ewp[(size_t)(p + j) * D + ch]);
        else ev = dot16u(pay + (size_t)(p + j) * 16, Wreg);
        t[j] = lrelu(xlv[j] + xrv + ev) * attv;
      }
#pragma unroll
      for (int mk = 1; mk <= 16; mk <<= 1) {
#pragma unroll
        for (int j = 0; j < 4; j++) t[j] += __shfl_xor(t[j], mk, 64);
      }
#pragma unroll
      for (int j = 0; j < 4; j++) {
        float ex = exp2f(t[j]);
        ssum += ex;
        acc += ex * xlv[j];
      }
    }
    for (; p < s1; ++p) {
      int c0 = __builtin_amdgcn_readfirstlane(csr_src[p]);
      float xlv = b2f(xl[(unsigned)c0 * D + ch]);
      float ev;
      if constexpr (PRE) ev = b2f(ewp[(size_t)p * D + ch]);
      else ev = dot16u(pay + (size_t)p * 16, Wreg);
      float t = lrelu(xlv + xrv + ev) * attv;
#pragma unroll
      for (int mk = 1; mk <= 16; mk <<= 1) t += __shfl_xor(t, mk, 64);
      float ex = exp2f(t);
      ssum += ex;
      acc += ex * xlv;
    }
    agg[(size_t)node * D + ch] = f2b(acc / (ssum + 1e-16f));
  } else {
    int node = wid * NPW + lane / D;
    int s0 = start[node], s1 = start[node + 1];
    int deg = s1 - s0;
    int last = s1 - 1;
    int degmax = max(deg, __shfl_xor(deg, 32, 64));
    float xrv = b2f(xr[(unsigned)node * D + ch]);
    float ssum = 0.f, acc = 0.f;
    for (int i = 0; i < degmax; i += 8) {
      int pp[8];
      bool av[8];
      int cc[8];
#pragma unroll
      for (int j = 0; j < 8; j++) {
        pp[j] = min(s0 + i + j, last);
        av[j] = (i + j) < deg;
      }
#pragma unroll
      for (int j = 0; j < 8; j++) cc[j] = csr_src[pp[j]];
      float xlv[8];
#pragma unroll
      for (int j = 0; j < 8; j++) xlv[j] = b2f(xl[(unsigned)cc[j] * D + ch]);
      float t[8];
#pragma unroll
      for (int j = 0; j < 8; j++) {
        float ev;
        if constexpr (PRE) ev = b2f(ewp[(size_t)pp[j] * D + ch]);
        else ev = dot16b(pay + (size_t)pp[j] * 16, Wreg);
        t[j] = lrelu(xlv[j] + xrv + ev) * attv;
      }
#pragma unroll
      for (int mk = 1; mk <= 16; mk <<= 1) {
#pragma unroll
        for (int j = 0; j < 8; j++) t[j] += __shfl_xor(t[j], mk, 64);
      }
#pragma unroll
      for (int j = 0; j < 8; j++) {
        float ex = av[j] ? exp2f(t[j]) : 0.f;
        ssum += ex;
        acc += ex * xlv[j];
      }
    }
    agg[(size_t)node * D + ch] = f2b(acc / (ssum + 1e-16f));
  }
}

// ===== tier-2 eid-indirect fused =====
template <int H, int C>
__global__ __launch_bounds__(256) void k_fusedg(
    const int* __restrict__ start, const uint2* __restrict__ csr,
    const void* __restrict__ eattr, const int* __restrict__ flg,
    const float* __restrict__ mean_sums,
    const u16* __restrict__ xl, const u16* __restrict__ xr,
    const void* We, const void* att, u16* __restrict__ agg) {
  constexpr int D = H * C;
  constexpr int NPW = 64 / D;
  bool wb = flg[1] != 0;
  bool eb = flg[2] != 0;
  int lane = threadIdx.x & 63;
  int ch = lane % D;
  float Wreg[16];
  if (wb) {
    const u16* Wp = (const u16*)We;
#pragma unroll
    for (int k = 0; k < 16; k++) Wreg[k] = b2f(Wp[k * D + ch]);
  } else {
    const float* Wp = (const float*)We;
#pragma unroll
    for (int k = 0; k < 16; k++) Wreg[k] = Wp[k * D + ch];
  }
  float attv = wb ? b2f(((const u16*)att)[ch]) : ((const float*)att)[ch];
  float ev_self = 0.f;
#pragma unroll
  for (int k = 0; k < 16; k++) ev_self += mean_sums[k] * (1.0f / NE) * Wreg[k];
  int wid = (blockIdx.x * 256 + threadIdx.x) >> 6;
  int node = wid * NPW + lane / D;
  int s0 = start[node], s1 = start[node + 1];
  int deg = s1 - s0;
  int last = s1 - 1;
  int degmax = deg;
  if constexpr (NPW == 2) degmax = max(deg, __shfl_xor(deg, 32, 64));
  float xrv = b2f(xr[(size_t)node * D + ch]);
  float ssum = 0.f, acc = 0.f;
  for (int i = 0; i < degmax; i += 2) {
    uint2 cr0 = csr[min(s0 + i, last)];
    uint2 cr1 = csr[min(s0 + i + 1, last)];
    bool a0 = i < deg, a1 = i + 1 < deg;
    float xlv0 = b2f(xl[(size_t)cr0.x * D + ch]);
    float xlv1 = b2f(xl[(size_t)cr1.x * D + ch]);
    float ev0 = cr0.y < NE ? (eb ? dot16b((const u16*)eattr + (size_t)cr0.y * 16, Wreg)
                                 : dot16f((const float*)eattr + (size_t)cr0.y * 16, Wreg))
                           : ev_self;
    float ev1 = cr1.y < NE ? (eb ? dot16b((const u16*)eattr + (size_t)cr1.y * 16, Wreg)
                                 : dot16f((const float*)eattr + (size_t)cr1.y * 16, Wreg))
                           : ev_self;
    float mv0 = xlv0 + xrv + ev0;
    float mv1 = xlv1 + xrv + ev1;
    mv0 = (mv0 > 0.f) ? mv0 : 0.2f * mv0;
    mv1 = (mv1 > 0.f) ? mv1 : 0.2f * mv1;
    float t0 = mv0 * attv, t1 = mv1 * attv;
#pragma unroll
    for (int mk = 1; mk <= 16; mk <<= 1) {
      t0 += __shfl_xor(t0, mk, 64);
      t1 += __shfl_xor(t1, mk, 64);
    }
    float ex0 = a0 ? __expf(t0) : 0.f;
    float ex1 = a1 ? __expf(t1) : 0.f;
    ssum += ex0 + ex1;
    acc += ex0 * xlv0 + ex1 * xlv1;
  }
  agg[(size_t)node * D + ch] = f2b(acc / (ssum + 1e-16f));
}

// ========== batch-norm reduce ==========
template <int D>
__global__ __launch_bounds__(256) void k_bnred(const u16* __restrict__ v,
                                               float* __restrict__ sum,
                                               float* __restrict__ sq, int M) {
  constexpr int RB = 256 / D;
  int tid = threadIdx.x;
  int c = tid % D;
  int rg = tid / D;
  float s = 0.f, q = 0.f;
  for (int r = blockIdx.x * RB + rg; r < M; r += gridDim.x * RB) {
    float x = b2f(v[(size_t)r * D + c]);
    s += x;
    q += x * x;
  }
  __shared__ float ls[256], lq[256];
  ls[tid] = s; lq[tid] = q;
  __syncthreads();
  if (tid < D) {
    float ts = 0.f, tq = 0.f;
    for (int i = tid; i < 256; i += D) { ts += ls[i]; tq += lq[i]; }
    atomicAdd(&sum[tid], ts);
    atomicAdd(&sq[tid], tq);
  }
}

// ========== batch-norm apply + skip + ELU (layer 1) ==========
template <int D>
__global__ __launch_bounds__(256) void k_bnapply(const u16* __restrict__ agg,
                                                 const u16* __restrict__ hp,
                                                 const float* __restrict__ sum,
                                                 const float* __restrict__ sq,
                                                 const void* g, const void* b,
                                                 const int* __restrict__ flg,
                                                 u16* __restrict__ out, int M) {
  bool wb = flg[1] != 0;
  int idx = blockIdx.x * 256 + threadIdx.x;
  if (idx >= M * D) return;
  int c = idx & (D - 1);
  float gc = wb ? b2f(((const u16*)g)[c]) : ((const float*)g)[c];
  float bc = wb ? b2f(((const u16*)b)[c]) : ((const float*)b)[c];
  float mu = sum[c] * (1.f / M);
  float var = fmaxf(sq[c] * (1.f / M) - mu * mu, 0.f);
  float sc = rsqrtf(var + 1e-5f) * gc;
  float v = (b2f(agg[idx]) - mu) * sc + bc + b2f(hp[idx]);
  v = v > 0.f ? v : expm1f(v);
  out[idx] = f2b(v);
}

// ========== D11a: BN2-apply + ELU + pool into NPOOL privatized copies ==========
// No fence, no done-counter: visibility via the D11b kernel boundary.
__global__ __launch_bounds__(256) void k_poolred(
    const u16* __restrict__ agg2, const u16* __restrict__ hp2,
    const float* __restrict__ sum, const float* __restrict__ sq,
    const void* g, const void* b, const int* __restrict__ flg,
    const int* __restrict__ batch,
    float* __restrict__ pool_sum, unsigned* __restrict__ pool_maxk,
    float* __restrict__ pool_cnt) {
  bool wb = flg[1] != 0;
  int c = threadIdx.x & 31;
  int rg = threadIdx.x >> 5;
  int cp = blockIdx.x & (NPOOL - 1);
  float* psum = pool_sum + cp * (NG * 32);
  unsigned* pmax = pool_maxk + cp * (NG * 32);
  float* pcnt = pool_cnt + cp * NG;
  float gc = wb ? b2f(((const u16*)g)[c]) : ((const float*)g)[c];
  float bc = wb ? b2f(((const u16*)b)[c]) : ((const float*)b)[c];
  float mu = sum[c] * (1.f / NN);
  float var = fmaxf(sq[c] * (1.f / NN) - mu * mu, 0.f);
  float scl = rsqrtf(var + 1e-5f) * gc;
  float sh = bc - mu * scl;

  const int NPB = 256;
  int n0 = blockIdx.x * NPB;
  int nend = min(n0 + NPB, NN);
  int cur = -1;
  float s = 0.f, mx = 0.f;
  int cnt = 0;
  for (int n = n0 + rg; n < nend; n += 8) {
    int gi = batch[n];
    float v = b2f(agg2[(size_t)n * 32 + c]) * scl + sh + b2f(hp2[(size_t)n * 32 + c]);
    v = v > 0.f ? v : expm1f(v);
    if (gi != cur) {
      if (cur >= 0) {
        atomicAdd(&psum[cur * 32 + c], s);
        atomicMax(&pmax[cur * 32 + c], f2key(mx));
        if (c == 0) atomicAdd(&pcnt[cur], (float)cnt);
      }
      cur = gi; s = 0.f; mx = -INFINITY; cnt = 0;
    }
    s += v;
    mx = fmaxf(mx, v);
    cnt++;
  }
  if (cur >= 0) {
    atomicAdd(&psum[cur * 32 + c], s);
    atomicMax(&pmax[cur * 32 + c], f2key(mx));
    if (c == 0) atomicAdd(&pcnt[cur], (float)cnt);
  }
}

// ========== D11b: reduce NPOOL copies -> output (1 block, plain loads) ==========
__global__ __launch_bounds__(256) void k_poolfin(
    const float* __restrict__ pool_sum, const unsigned* __restrict__ pool_maxk,
    const float* __restrict__ pool_cnt, const int* __restrict__ flg,
    void* __restrict__ out) {
  bool ob = flg[3] != 0;
  for (int idx = threadIdx.x; idx < NG * 64; idx += 256) {
    int gi = idx / 64, cc = idx % 64;
    float cntv = 0.f;
#pragma unroll
    for (int k = 0; k < NPOOL; k++) cntv += pool_cnt[k * NG + gi];
    float val;
    if (cc < 32) {
      float s = 0.f;
#pragma unroll
      for (int k = 0; k < NPOOL; k++) s += pool_sum[k * (NG * 32) + gi * 32 + cc];
      val = s / fmaxf(cntv, 1.f);
    } else {
      unsigned km = 0u;
#pragma unroll
      for (int k = 0; k < NPOOL; k++)
        km = max(km, pool_maxk[k * (NG * 32) + gi * 32 + (cc - 32)]);
      val = cntv > 0.f ? key2f(km) : 0.f;
    }
    if (ob) ((u16*)out)[idx] = f2b(val);
    else ((float*)out)[idx] = val;
  }
}

extern "C" void kernel_launch(void* const* d_in, const int* in_sizes, int n_in,
                              void* d_out, int out_size, void* d_ws, size_t ws_size,
                              hipStream_t stream) {
  (void)in_sizes; (void)n_in; (void)out_size;
  const void* x     = d_in[0];
  const int*  ei    = (const int*)d_in[1];
  const void* eattr = d_in[2];
  const int*  batch = (const int*)d_in[3];
  const void* skip1_W = d_in[4];
  const void* skip1_b = d_in[5];
  const void* c1_Wl = d_in[6];
  const void* c1_bl = d_in[7];
  const void* c1_Wr = d_in[8];
  const void* c1_br = d_in[9];
  const void* c1_We = d_in[10];
  const void* c1_att = d_in[11];
  const void* bn1_g = d_in[13];
  const void* bn1_b = d_in[14];
  const void* skip2_W = d_in[15];
  const void* skip2_b = d_in[16];
  const void* c2_Wl = d_in[17];
  const void* c2_bl = d_in[18];
  const void* c2_Wr = d_in[19];
  const void* c2_br = d_in[20];
  const void* c2_We = d_in[21];
  const void* c2_att = d_in[22];
  const void* bn2_g = d_in[24];
  const void* bn2_b = d_in[25];

  float* ws = (float*)d_ws;
  size_t off = 0;
  auto alloc = [&](size_t nfl) {
    float* p = ws + off;
    off += (nfl + 15) & ~(size_t)15;
    return p;
  };
  // ---- zero-initialized region ----
  int*   flags      = (int*)alloc(16);
  float* mean_sums  = alloc(16);
  float* mean_part  = alloc(64 * 16);
  int*   deg8       = (int*)alloc((size_t)NDEG * NN);
  float* bnsum1     = alloc(64);
  float* bnsq1      = alloc(64);
  float* bnsum2     = alloc(32);
  float* bnsq2      = alloc(32);
  float* pool_cnt   = alloc((size_t)NPOOL * NG);
  float* pool_sum   = alloc((size_t)NPOOL * NG * 32);
  unsigned* pool_maxk = (unsigned*)alloc((size_t)NPOOL * NG * 32);
  size_t zcnt16 = (off * sizeof(float)) / 16;
  // ---- common (not zeroed) ----
  int*   tile_tot = (int*)alloc(64);
  u16* xh  = (u16*)alloc((size_t)NN * 64);
  u16* xlo = (u16*)alloc((size_t)NN * 64);
  size_t zoff = off;

  // ---- tier 0: CSR payload + precomputed EW (~233 MB) ----
  int* start   = (int*)alloc(NN + 1);
  int* cursor  = (int*)alloc(NN);
  int* csr_src = (int*)alloc(ETOT);
  u16* ea16    = (u16*)alloc((size_t)ETOT * 8);
  u16* ew1     = (u16*)alloc((size_t)ETOT * 32);  // [ETOT][64] bf16
  u16* ew2     = (u16*)alloc((size_t)ETOT * 16);  // [ETOT][32] bf16
  uint2* csr = nullptr;
  u16* xl1 = (u16*)alloc((size_t)NN * 32);
  u16* xr1 = (u16*)alloc((size_t)NN * 32);
  u16* hp1 = (u16*)alloc((size_t)NN * 32);
  u16* agg = (u16*)alloc((size_t)NN * 32);
  int tier = 0;
  if (off * sizeof(float) > ws_size) {
    tier = 1;
    off = zoff;
    start   = (int*)alloc(NN + 1);
    cursor  = (int*)alloc(NN);
    csr_src = (int*)alloc(ETOT);
    ea16    = (u16*)alloc((size_t)ETOT * 8);
    ew1 = ew2 = nullptr;
    xl1 = (u16*)alloc((size_t)NN * 32);
    xr1 = (u16*)alloc((size_t)NN * 32);
    hp1 = (u16*)alloc((size_t)NN * 32);
    agg = (u16*)alloc((size_t)NN * 32);
  }
  if (tier == 1 && off * sizeof(float) > ws_size) {
    tier = 2;
    off = zoff;
    start   = (int*)alloc(NN + 1);
    cursor  = (int*)alloc(NN);
    csr     = (uint2*)alloc((size_t)ETOT * 2);
    ea16    = nullptr;
    xl1 = (u16*)alloc((size_t)NN * 32);
    xr1 = (u16*)alloc((size_t)NN * 32);
    hp1 = (u16*)alloc((size_t)NN * 32);
    agg = (u16*)alloc((size_t)NN * 32);
  }
  u16* h1  = xr1;
  u16* xl2 = xl1;
  u16* xr2 = xl1 + (size_t)NN * 32;
  u16* hp2 = hp1;

  int eg = (ETOT + 255) / 256;

  // D1: zero + detect
  k_init<<<128, 256, 0, stream>>>((uint4*)d_ws, (int)zcnt16,
                                  (const unsigned*)x, (const unsigned*)skip1_W,
                                  (const unsigned*)eattr, flags);
  // D2a: deg scatter (tiny waves, pure TLP)
  k_hist<<<eg, 256, 0, stream>>>(ei, deg8);
  // D2: colsum + x split (pure streaming)
  k_colsum_xsplit<<<2048, 256, 0, stream>>>(eattr, x, flags, mean_part, xh, xlo);
  // D2b: per-tile degree sums (parallel)
  k_scansum<<<SCAN_NT, 256, 0, stream>>>(deg8, mean_part, mean_sums, tile_tot);
  // D2c: prefix + write start/cursor (parallel)
  k_scanwrite<<<SCAN_NT, 256, 0, stream>>>(deg8, tile_tot, start, cursor);
  // D3: lin3 L1 (pure GEMM)
  k_lin1<128, 64, 625, 5><<<1875, 256, 0, stream>>>(
      x, xh, xlo, flags, c1_Wl, c1_Wr, skip1_W,
      c1_bl, c1_br, skip1_b, xl1, xr1, hp1);
  // D4: CSR build
  if (tier <= 1) {
    k_buildcsr_pay<<<eg, 256, 0, stream>>>(ei, eattr, flags, mean_sums,
                                           cursor, csr_src, ea16);
  } else {
    k_buildcsr<<<eg, 256, 0, stream>>>(ei, cursor, csr);
  }
  // D4c: EW precompute GEMM (tier 0 only)
  if (tier == 0) {
    k_ewgemm<<<1024, 256, 0, stream>>>(ea16, flags, c1_We, c2_We, ew1, ew2);
  }
  // D5: fused L1
  if (tier == 0) {
    k_fusedp<2, 32, true><<<NN / 4, 256, 0, stream>>>(start, csr_src, ea16, ew1,
                                                      flags, xl1, xr1, c1_We,
                                                      c1_att, agg);
  } else if (tier == 1) {
    k_fusedp<2, 32, false><<<NN / 4, 256, 0, stream>>>(start, csr_src, ea16, nullptr,
                                                       flags, xl1, xr1, c1_We,
                                                       c1_att, agg);
  } else {
    k_fusedg<2, 32><<<NN / 4, 256, 0, stream>>>(start, csr, eattr, flags, mean_sums,
                                                xl1, xr1, c1_We, c1_att, agg);
  }
  // D6: bnred L1
  k_bnred<64><<<256, 256, 0, stream>>>(agg, bnsum1, bnsq1, NN);
  // D7: bn apply L1
  k_bnapply<64><<<(NN * 64 + 255) / 256, 256, 0, stream>>>(agg, hp1, bnsum1, bnsq1,
                                                           bn1_g, bn1_b, flags, h1, NN);
  // D8: lin3 L2 (LDS-free MFMA)
  {
    dim3 g(625, 3);
    k_lin3b<64, 32, 5><<<g, 256, 0, stream>>>(h1, flags, c2_Wl, c2_Wr, skip2_W,
                                              c2_bl, c2_br, skip2_b,
                                              xl2, xr2, hp2, NN);
  }
  // D9: fused L2
  if (tier == 0) {
    k_fusedp<1, 32, true><<<NN / 8, 256, 0, stream>>>(start, csr_src, ea16, ew2,
                                                      flags, xl2, xr2, c2_We,
                                                      c2_att, agg);
  } else if (tier == 1) {
    k_fusedp<1, 32, false><<<NN / 8, 256, 0, stream>>>(start, csr_src, ea16, nullptr,
                                                       flags, xl2, xr2, c2_We,
                                                       c2_att, agg);
  } else {
    k_fusedg<1, 32><<<NN / 8, 256, 0, stream>>>(start, csr, eattr, flags, mean_sums,
                                                xl2, xr2, c2_We, c2_att, agg);
  }
  // D10: bnred L2
  k_bnred<32><<<256, 256, 0, stream>>>(agg, bnsum2, bnsq2, NN);
  // D11a: bn2 apply + pool into privatized copies (no fence)
  k_poolred<<<(NN + 255) / 256, 256, 0, stream>>>(agg, hp2, bnsum2, bnsq2,
                                                  bn2_g, bn2_b, flags, batch,
                                                  pool_sum, pool_maxk, pool_cnt);
  // D11b: reduce copies -> output (kernel-boundary visibility)
  k_poolfin<<<1, 256, 0, stream>>>(pool_sum, pool_maxk, pool_cnt, flags, d_out);
}

// Round 12
// 498.845 us; speedup vs baseline: 1.1121x; 1.0334x over previous
//
#include <hip/hip_runtime.h>
#include <hip/hip_bf16.h>

#define NE 800000
#define NN 50000
#define NG 16
#define ETOT (NE + NN)

typedef unsigned short u16;
typedef __attribute__((ext_vector_type(8))) short short8;
typedef __attribute__((ext_vector_type(4))) float float4v;

__device__ __forceinline__ float b2f(u16 u) {
  return __uint_as_float(((unsigned)u) << 16);
}
__device__ __forceinline__ u16 f2b(float f) {
  __hip_bfloat16 b = __float2bfloat16(f);
  return *(u16*)&b;
}
__device__ __forceinline__ void cv8(uint4 v, float* o) {
  o[0] = __uint_as_float(v.x << 16);
  o[1] = __uint_as_float(v.x & 0xFFFF0000u);
  o[2] = __uint_as_float(v.y << 16);
  o[3] = __uint_as_float(v.y & 0xFFFF0000u);
  o[4] = __uint_as_float(v.z << 16);
  o[5] = __uint_as_float(v.z & 0xFFFF0000u);
  o[6] = __uint_as_float(v.w << 16);
  o[7] = __uint_as_float(v.w & 0xFFFF0000u);
}
__device__ __forceinline__ unsigned pk2(float a, float b) {
  return (unsigned)f2b(a) | ((unsigned)f2b(b) << 16);
}
__device__ __forceinline__ unsigned f2key(float f) {
  unsigned u = __float_as_uint(f);
  return (u & 0x80000000u) ? ~u : (u | 0x80000000u);
}
__device__ __forceinline__ float key2f(unsigned k) {
  unsigned u = (k & 0x80000000u) ? (k ^ 0x80000000u) : ~k;
  return __uint_as_float(u);
}
__device__ __forceinline__ int plaus(unsigned h) {
  unsigned eh = (h >> 7) & 0xFF;
  return (h == 0) || (eh >= 100 && eh <= 140);
}
__device__ __forceinline__ float lrelu(float v) {
  return (v > 0.f) ? v : 0.2f * v;
}

#define NDEG 8   // deg privatization copies
#define NPOOL 16 // pool privatization copies
#define LOG2E 1.4426950408889634f

// ========== D1: zero accumulator region + dtype detect (block 0; NO fence) ==========
__global__ __launch_bounds__(256) void k_init(uint4* __restrict__ zbase, int zcnt16,
                                              const unsigned* __restrict__ a,
                                              const unsigned* __restrict__ b,
                                              const unsigned* __restrict__ c,
                                              int* __restrict__ flags) {
  uint4 z = {0, 0, 0, 0};
  for (int i = blockIdx.x * 256 + threadIdx.x; i < zcnt16; i += gridDim.x * 256)
    zbase[i] = z;
  if (blockIdx.x != 0) return;
  __shared__ int cnt[3];
  if (threadIdx.x < 3) cnt[threadIdx.x] = 0;
  __syncthreads();
  const unsigned* arr[3] = {a, b, c};
  for (int k = 0; k < 3; k++) {
    int ok = 0;
    for (int i = threadIdx.x; i < 4096; i += 256) {
      unsigned w = arr[k][i];
      ok += (plaus(w & 0xFFFFu) && plaus(w >> 16)) ? 1 : 0;
    }
    atomicAdd(&cnt[k], ok);
  }
  __syncthreads();
  if (threadIdx.x == 0) {
    int f0 = cnt[0] > 2048, f1 = cnt[1] > 2048, f2 = cnt[2] > 2048;
    flags[0] = f0;
    flags[1] = f1;
    flags[2] = f2;
    flags[3] = f0 && f1 && f2;
  }
}

// ========== D2a: deg scatter ONLY (8-way privatized) ==========
__global__ __launch_bounds__(256) void k_hist(const int* __restrict__ ei,
                                              int* __restrict__ deg8) {
  int gt = blockIdx.x * 256 + threadIdx.x;
  if (gt >= ETOT) return;
  int dst = (gt < NE) ? ei[NE + gt] : gt - NE;
  atomicAdd(&deg8[(blockIdx.x & (NDEG - 1)) * NN + dst], 1);
}

// ========== D2: edge_attr colsums + x hi/lo bf16 split (pure streaming) ==========
__global__ __launch_bounds__(256) void k_colsum_xsplit(
    const void* __restrict__ ea, const void* __restrict__ xin,
    const int* __restrict__ flg, float* __restrict__ mean_part,
    u16* __restrict__ xh, u16* __restrict__ xlo) {
  int gt = blockIdx.x * 256 + threadIdx.x;
  bool eb = flg[2] != 0;
  int col = gt & 15;
  int row = gt >> 4;
  int rstride = (gridDim.x * 256) >> 4;
  float s = 0.f;
  if (eb) {
    const u16* p = (const u16*)ea;
    for (int e = row; e < NE; e += rstride) s += b2f(p[(size_t)e * 16 + col]);
  } else {
    const float* p = (const float*)ea;
    for (int e = row; e < NE; e += rstride) s += p[(size_t)e * 16 + col];
  }
  __shared__ float ls[256];
  ls[threadIdx.x] = s;
  __syncthreads();
  if (threadIdx.x < 16) {
    float t = 0.f;
    for (int i = threadIdx.x; i < 256; i += 16) t += ls[i];
    atomicAdd(&mean_part[(blockIdx.x & 63) * 16 + threadIdx.x], t);
  }
  if (flg[0] == 0) {
    const float4* xp4 = (const float4*)xin;
    const int nch = NN * 32;
    int stride = gridDim.x * 256;
    for (int i = gt; i < nch; i += stride) {
      float4 v = xp4[i];
      u16 h0 = f2b(v.x), h1 = f2b(v.y), h2 = f2b(v.z), h3 = f2b(v.w);
      u16 l0 = f2b(v.x - b2f(h0));
      u16 l1 = f2b(v.y - b2f(h1));
      u16 l2 = f2b(v.z - b2f(h2));
      u16 l3 = f2b(v.w - b2f(h3));
      uint2 ho, lo2;
      ho.x = (unsigned)h0 | ((unsigned)h1 << 16);
      ho.y = (unsigned)h2 | ((unsigned)h3 << 16);
      lo2.x = (unsigned)l0 | ((unsigned)l1 << 16);
      lo2.y = (unsigned)l2 | ((unsigned)l3 << 16);
      *(uint2*)(xh + (size_t)i * 4) = ho;
      *(uint2*)(xlo + (size_t)i * 4) = lo2;
    }
  }
}

#define SCAN_NT ((NN + 1023) / 1024)  // 49

// ========== D2b: per-tile degree sums (49 blocks) ==========
__global__ __launch_bounds__(256) void k_scansum(const int* __restrict__ deg8,
                                                 const float* __restrict__ mean_part,
                                                 float* __restrict__ mean_sums,
                                                 int* __restrict__ tile_tot) {
  int t = threadIdx.x;
  if (blockIdx.x == 0 && t < 16) {
    float s = 0.f;
#pragma unroll
    for (int j = 0; j < 64; j++) s += mean_part[j * 16 + t];
    mean_sums[t] = s;
  }
  int lane = t & 63;
  int wv = t >> 6;
  int idx = blockIdx.x * 1024 + t * 4;
  int s4 = 0;
  if (idx + 3 < NN) {
#pragma unroll
    for (int c = 0; c < NDEG; c++) {
      int4 dc = *(const int4*)(deg8 + c * NN + idx);
      s4 += dc.x + dc.y + dc.z + dc.w;
    }
  } else {
#pragma unroll
    for (int c = 0; c < NDEG; c++) {
      if (idx + 0 < NN) s4 += deg8[c * NN + idx + 0];
      if (idx + 1 < NN) s4 += deg8[c * NN + idx + 1];
      if (idx + 2 < NN) s4 += deg8[c * NN + idx + 2];
      if (idx + 3 < NN) s4 += deg8[c * NN + idx + 3];
    }
  }
  int r = s4;
#pragma unroll
  for (int ofs = 1; ofs < 64; ofs <<= 1) r += __shfl_xor(r, ofs, 64);
  __shared__ int wsum[4];
  if (lane == 0) wsum[wv] = r;
  __syncthreads();
  if (t == 0) tile_tot[blockIdx.x] = wsum[0] + wsum[1] + wsum[2] + wsum[3];
}

// ========== D2c: prefix bases + per-tile scan + start/cursor write (49 blocks) ==========
__global__ __launch_bounds__(256) void k_scanwrite(const int* __restrict__ deg8,
                                                   const int* __restrict__ tile_tot,
                                                   int* __restrict__ start,
                                                   int* __restrict__ cursor) {
  __shared__ int sbase;
  __shared__ int wsum[4];
  int t = threadIdx.x;
  int lane = t & 63;
  int wv = t >> 6;
  if (wv == 0) {
    int v = (lane < SCAN_NT) ? tile_tot[lane] : 0;
    int sc = v;
#pragma unroll
    for (int ofs = 1; ofs < 64; ofs <<= 1) {
      int u = __shfl_up(sc, ofs, 64);
      if (lane >= ofs) sc += u;
    }
    if (lane == (int)blockIdx.x) sbase = sc - v;
    if (blockIdx.x == 0 && lane == SCAN_NT - 1) start[NN] = sc;
  }
  int idx = blockIdx.x * 1024 + t * 4;
  int4 d = {0, 0, 0, 0};
  if (idx + 3 < NN) {
#pragma unroll
    for (int c = 0; c < NDEG; c++) {
      int4 dc = *(const int4*)(deg8 + c * NN + idx);
      d.x += dc.x; d.y += dc.y; d.z += dc.z; d.w += dc.w;
    }
  } else {
#pragma unroll
    for (int c = 0; c < NDEG; c++) {
      if (idx + 0 < NN) d.x += deg8[c * NN + idx + 0];
      if (idx + 1 < NN) d.y += deg8[c * NN + idx + 1];
      if (idx + 2 < NN) d.z += deg8[c * NN + idx + 2];
      if (idx + 3 < NN) d.w += deg8[c * NN + idx + 3];
    }
  }
  int s4 = d.x + d.y + d.z + d.w;
  int sc = s4;
#pragma unroll
  for (int ofs = 1; ofs < 64; ofs <<= 1) {
    int v = __shfl_up(sc, ofs, 64);
    if (lane >= ofs) sc += v;
  }
  if (lane == 63) wsum[wv] = sc;
  __syncthreads();
  int wbase = 0;
#pragma unroll
  for (int w = 0; w < 4; w++)
    if (w < wv) wbase += wsum[w];
  int excl = sbase + wbase + (sc - s4);
  int4 st;
  st.x = excl;
  st.y = excl + d.x;
  st.z = st.y + d.y;
  st.w = st.z + d.z;
  if (idx + 3 < NN) {
    *(int4*)(start + idx) = st;
    *(int4*)(cursor + idx) = st;
  } else {
    if (idx + 0 < NN) { start[idx + 0] = st.x; cursor[idx + 0] = st.x; }
    if (idx + 1 < NN) { start[idx + 1] = st.y; cursor[idx + 1] = st.y; }
    if (idx + 2 < NN) { start[idx + 2] = st.z; cursor[idx + 2] = st.z; }
    if (idx + 3 < NN) { start[idx + 3] = st.w; cursor[idx + 3] = st.w; }
  }
}

// ===== LDS-free split-bf16 MFMA GEMM tile =====
template <int K, int N, int RPB>
__device__ __forceinline__ void gemm_direct(
    const void* __restrict__ W, const void* __restrict__ bb, bool wb,
    const u16* __restrict__ xh, const u16* __restrict__ xlo, bool has_lo,
    u16* __restrict__ out, int tile) {
  constexpr int CT = N / 16;
  constexpr int WPC = 4 / CT;
  constexpr int KK = K / 32;
  int lane = threadIdx.x & 63;
  int wave = threadIdx.x >> 6;
  int col = lane & 15;
  int quad = lane >> 4;
  int ct = wave % CT;
  int rt_off = wave / CT;
  short8 bh[KK], bl[KK];
#pragma unroll
  for (int kk = 0; kk < KK; kk++) {
    short8 th, tl;
#pragma unroll
    for (int j = 0; j < 8; j++) {
      int k = kk * 32 + quad * 8 + j;
      float w = wb ? b2f(((const u16*)W)[k * N + ct * 16 + col])
                   : ((const float*)W)[k * N + ct * 16 + col];
      u16 hb = f2b(w);
      th[j] = (short)hb;
      tl[j] = (short)f2b(w - b2f(hb));
    }
    bh[kk] = th;
    bl[kk] = tl;
  }
  float bias = wb ? b2f(((const u16*)bb)[ct * 16 + col])
                  : ((const float*)bb)[ct * 16 + col];
  int rt0 = tile * RPB;
  for (int i = rt_off; i < RPB; i += WPC) {
    int rt = rt0 + i;
    int row = rt * 16 + col;
    float4v acc = {0.f, 0.f, 0.f, 0.f};
#pragma unroll
    for (int kk = 0; kk < KK; kk++) {
      short8 afh = *(const short8*)(xh + (size_t)row * K + kk * 32 + quad * 8);
      acc = __builtin_amdgcn_mfma_f32_16x16x32_bf16(afh, bh[kk], acc, 0, 0, 0);
      if (has_lo) {
        short8 afl = *(const short8*)(xlo + (size_t)row * K + kk * 32 + quad * 8);
        acc = __builtin_amdgcn_mfma_f32_16x16x32_bf16(afl, bh[kk], acc, 0, 0, 0);
      }
      if (!wb)
        acc = __builtin_amdgcn_mfma_f32_16x16x32_bf16(afh, bl[kk], acc, 0, 0, 0);
    }
#pragma unroll
    for (int r = 0; r < 4; r++) {
      int orow = rt * 16 + quad * 4 + r;
      out[(size_t)orow * N + ct * 16 + col] = f2b(acc[r] + bias);
    }
  }
}

// ========== D3: lin3 L1 (pure GEMM) ==========
template <int K, int N, int TILES, int RPB>
__global__ __launch_bounds__(256) void k_lin1(
    const void* __restrict__ xin, const u16* __restrict__ xh,
    const u16* __restrict__ xlo, const int* __restrict__ flg,
    const void* W0, const void* W1, const void* W2,
    const void* b0, const void* b1, const void* b2,
    u16* __restrict__ o0, u16* __restrict__ o1, u16* __restrict__ o2) {
  int lidx = blockIdx.x;
  int wset = lidx / TILES;
  int tile = lidx % TILES;
  bool wb = flg[1] != 0;
  bool xb = flg[0] != 0;
  const void* W = wset == 0 ? W0 : (wset == 1 ? W1 : W2);
  const void* bb = wset == 0 ? b0 : (wset == 1 ? b1 : b2);
  u16* out = wset == 0 ? o0 : (wset == 1 ? o1 : o2);
  const u16* ah = xb ? (const u16*)xin : xh;
  gemm_direct<K, N, RPB>(W, bb, wb, ah, xlo, !xb, out, tile);
}

// ========== D4: CSR build ==========
__global__ __launch_bounds__(256) void k_buildcsr_pay(
    const int* __restrict__ ei, const void* __restrict__ eattr,
    const int* __restrict__ flg, const float* __restrict__ mean_sums,
    int* __restrict__ cursor, int* __restrict__ csr_src,
    u16* __restrict__ ea16) {
  int e = blockIdx.x * 256 + threadIdx.x;
  if (e >= ETOT) return;
  bool eb = flg[2] != 0;
  int src, dst;
  if (e < NE) { src = ei[e]; dst = ei[NE + e]; } else { src = dst = e - NE; }
  float rec[16];
  if (e < NE) {
    if (eb) {
      const uint4* q = (const uint4*)((const u16*)eattr + (size_t)e * 16);
      cv8(q[0], rec);
      cv8(q[1], rec + 8);
    } else {
      const float* q = (const float*)eattr + (size_t)e * 16;
#pragma unroll
      for (int k = 0; k < 16; k++) rec[k] = q[k];
    }
  } else {
#pragma unroll
    for (int k = 0; k < 16; k++) rec[k] = mean_sums[k] * (1.0f / NE);
  }
  int pos = atomicAdd(&cursor[dst], 1);
  csr_src[pos] = src;
  u16 rb[16];
#pragma unroll
  for (int k = 0; k < 16; k++) rb[k] = f2b(rec[k]);
  uint4* dp = (uint4*)(ea16 + (size_t)pos * 16);
  dp[0] = *(uint4*)rb;
  dp[1] = *(uint4*)(rb + 8);
}

__global__ __launch_bounds__(256) void k_buildcsr(const int* __restrict__ ei,
                                                  int* __restrict__ cursor,
                                                  uint2* __restrict__ csr) {
  int e = blockIdx.x * 256 + threadIdx.x;
  if (e >= ETOT) return;
  int src, dst;
  if (e < NE) { src = ei[e]; dst = ei[NE + e]; } else { src = dst = e - NE; }
  int pos = atomicAdd(&cursor[dst], 1);
  uint2 r; r.x = (unsigned)src; r.y = (unsigned)e;
  csr[pos] = r;
}

// ========== D4c: EW = payload @ We GEMM (tier0 only) ==========
__global__ __launch_bounds__(256) void k_ewgemm(
    const u16* __restrict__ ea, const int* __restrict__ flg,
    const void* We1, const void* We2,
    u16* __restrict__ ew1, u16* __restrict__ ew2) {
  bool wb = flg[1] != 0;
  int lane = threadIdx.x & 63;
  int col = lane & 15;
  int quad = lane >> 4;
  short8 b1h[4], b1l[4], b2h[2], b2l[2];
#pragma unroll
  for (int ct = 0; ct < 4; ct++) {
    short8 th, tl;
#pragma unroll
    for (int j = 0; j < 8; j++) {
      int k = quad * 8 + j;
      float w = 0.f;
      if (k < 16)
        w = wb ? b2f(((const u16*)We1)[k * 64 + ct * 16 + col])
               : ((const float*)We1)[k * 64 + ct * 16 + col];
      u16 hb = f2b(w);
      th[j] = (short)hb;
      tl[j] = (short)f2b(w - b2f(hb));
    }
    b1h[ct] = th; b1l[ct] = tl;
  }
#pragma unroll
  for (int ct = 0; ct < 2; ct++) {
    short8 th, tl;
#pragma unroll
    for (int j = 0; j < 8; j++) {
      int k = quad * 8 + j;
      float w = 0.f;
      if (k < 16)
        w = wb ? b2f(((const u16*)We2)[k * 32 + ct * 16 + col])
               : ((const float*)We2)[k * 32 + ct * 16 + col];
      u16 hb = f2b(w);
      th[j] = (short)hb;
      tl[j] = (short)f2b(w - b2f(hb));
    }
    b2h[ct] = th; b2l[ct] = tl;
  }
  int nw = (gridDim.x * 256) >> 6;
  int wid = (blockIdx.x * 256 + threadIdx.x) >> 6;
  const int NT = ETOT / 16;  // 53125 exact
  for (int rt = wid; rt < NT; rt += nw) {
    int row = rt * 16 + col;
    short8 af = {0, 0, 0, 0, 0, 0, 0, 0};
    if (quad < 2) af = *(const short8*)(ea + (size_t)row * 16 + quad * 8);
#pragma unroll
    for (int ct = 0; ct < 4; ct++) {
      float4v acc = {0.f, 0.f, 0.f, 0.f};
      acc = __builtin_amdgcn_mfma_f32_16x16x32_bf16(af, b1h[ct], acc, 0, 0, 0);
      acc = __builtin_amdgcn_mfma_f32_16x16x32_bf16(af, b1l[ct], acc, 0, 0, 0);
#pragma unroll
      for (int r = 0; r < 4; r++)
        ew1[(size_t)(rt * 16 + quad * 4 + r) * 64 + ct * 16 + col] = f2b(acc[r]);
    }
#pragma unroll
    for (int ct = 0; ct < 2; ct++) {
      float4v acc = {0.f, 0.f, 0.f, 0.f};
      acc = __builtin_amdgcn_mfma_f32_16x16x32_bf16(af, b2h[ct], acc, 0, 0, 0);
      acc = __builtin_amdgcn_mfma_f32_16x16x32_bf16(af, b2l[ct], acc, 0, 0, 0);
#pragma unroll
      for (int r = 0; r < 4; r++)
        ew2[(size_t)(rt * 16 + quad * 4 + r) * 32 + ct * 16 + col] = f2b(acc[r]);
    }
  }
}

// ==== standalone lin3 (layer 2) — LDS-free; xin (h1) always bf16 ====
template <int K, int N, int RPB>
__global__ __launch_bounds__(256) void k_lin3b(
    const void* __restrict__ xin, const int* __restrict__ flg,
    const void* W0, const void* W1, const void* W2,
    const void* b0, const void* b1, const void* b2,
    u16* __restrict__ o0, u16* __restrict__ o1, u16* __restrict__ o2, int M) {
  (void)M;
  bool wb = flg[1] != 0;
  const void* W = blockIdx.y == 0 ? W0 : (blockIdx.y == 1 ? W1 : W2);
  const void* bb = blockIdx.y == 0 ? b0 : (blockIdx.y == 1 ? b1 : b2);
  u16* out = blockIdx.y == 0 ? o0 : (blockIdx.y == 1 ? o1 : o2);
  gemm_direct<K, N, RPB>(W, bb, wb, (const u16*)xin, nullptr, false, out,
                         blockIdx.x);
}

// ===== payload dots =====
__device__ __forceinline__ float dot16b(const u16* __restrict__ p,
                                        const float* __restrict__ W) {
  float ea[16];
  const uint4* q = (const uint4*)p;
  cv8(q[0], ea);
  cv8(q[1], ea + 8);
  float s = 0.f;
#pragma unroll
  for (int k = 0; k < 16; k++) s += ea[k] * W[k];
  return s;
}
__device__ __forceinline__ float dot16f(const float* __restrict__ q,
                                        const float* __restrict__ W) {
  float s = 0.f;
#pragma unroll
  for (int k = 0; k < 16; k++) s += q[k] * W[k];
  return s;
}

// ===== D5/D9: fused attention + softmax gather-reduce =====
// 2 channels per lane: GL = D/2 lanes per node, NPW = 64/GL nodes per wave.
// Head sums reduce within 16-lane subgroups (4 shuffle steps) for both layers:
//   D5 (H=2,C=32): GL=32; j<16 = head0 (ch 0..31), j>=16 = head1. NPW=2.
//   D9 (H=1,C=32): GL=16; whole group = the head. NPW=4.
template <int H, int C, bool PRE>
__global__ __launch_bounds__(256) void k_fusedp(
    const int* __restrict__ start, const int* __restrict__ csr_src,
    const u16* __restrict__ pay, const u16* __restrict__ ewp,
    const int* __restrict__ flg,
    const u16* __restrict__ xl, const u16* __restrict__ xr,
    const void* We, const void* att, u16* __restrict__ agg) {
  constexpr int D = H * C;
  constexpr int GL = D / 2;        // lanes per node
  constexpr int NPW = 64 / GL;     // nodes per wave
  bool wb = flg[1] != 0;
  int lane = threadIdx.x & 63;
  int j = lane % GL;               // channel-pair index
  int ch0 = 2 * j;                 // channels (ch0, ch0+1)
  float Wreg0[16], Wreg1[16];
  if constexpr (!PRE) {
    if (wb) {
      const u16* Wp = (const u16*)We;
#pragma unroll
      for (int k = 0; k < 16; k++) {
        Wreg0[k] = b2f(Wp[k * D + ch0]);
        Wreg1[k] = b2f(Wp[k * D + ch0 + 1]);
      }
    } else {
      const float* Wp = (const float*)We;
#pragma unroll
      for (int k = 0; k < 16; k++) {
        Wreg0[k] = Wp[k * D + ch0];
        Wreg1[k] = Wp[k * D + ch0 + 1];
      }
    }
  }
  float attv0, attv1;
  if (wb) {
    attv0 = b2f(((const u16*)att)[ch0]) * LOG2E;
    attv1 = b2f(((const u16*)att)[ch0 + 1]) * LOG2E;
  } else {
    attv0 = ((const float*)att)[ch0] * LOG2E;
    attv1 = ((const float*)att)[ch0 + 1] * LOG2E;
  }
  int wid = (blockIdx.x * 256 + threadIdx.x) >> 6;
  int node = wid * NPW + lane / GL;
  int s0 = start[node], s1 = start[node + 1];
  int deg = s1 - s0;
  int last = s1 - 1;
  int degmax = deg;
#pragma unroll
  for (int m = GL; m < 64; m <<= 1)
    degmax = max(degmax, __shfl_xor(degmax, m, 64));
  // xr channel pair (one dword)
  unsigned xru = *(const unsigned*)(xr + (size_t)node * D + ch0);
  float xr0 = __uint_as_float(xru << 16);
  float xr1 = __uint_as_float(xru & 0xFFFF0000u);
  float ssum = 0.f, acc0 = 0.f, acc1 = 0.f;
  for (int i = 0; i < degmax; i += 4) {
    int pp[4];
    bool av[4];
    int cc[4];
#pragma unroll
    for (int u = 0; u < 4; u++) {
      pp[u] = min(s0 + i + u, last);
      av[u] = (i + u) < deg;
    }
#pragma unroll
    for (int u = 0; u < 4; u++) cc[u] = csr_src[pp[u]];
    unsigned xlu[4];
#pragma unroll
    for (int u = 0; u < 4; u++)
      xlu[u] = *(const unsigned*)(xl + (size_t)(unsigned)cc[u] * D + ch0);
    float t[4], xl0[4], xl1[4];
#pragma unroll
    for (int u = 0; u < 4; u++) {
      xl0[u] = __uint_as_float(xlu[u] << 16);
      xl1[u] = __uint_as_float(xlu[u] & 0xFFFF0000u);
      float ev0, ev1;
      if constexpr (PRE) {
        unsigned ewu = *(const unsigned*)(ewp + (size_t)pp[u] * D + ch0);
        ev0 = __uint_as_float(ewu << 16);
        ev1 = __uint_as_float(ewu & 0xFFFF0000u);
      } else {
        ev0 = dot16b(pay + (size_t)pp[u] * 16, Wreg0);
        ev1 = dot16b(pay + (size_t)pp[u] * 16, Wreg1);
      }
      t[u] = lrelu(xl0[u] + xr0 + ev0) * attv0 +
             lrelu(xl1[u] + xr1 + ev1) * attv1;
    }
#pragma unroll
    for (int mk = 1; mk <= 8; mk <<= 1) {
#pragma unroll
      for (int u = 0; u < 4; u++) t[u] += __shfl_xor(t[u], mk, 64);
    }
#pragma unroll
    for (int u = 0; u < 4; u++) {
      float ex = av[u] ? exp2f(t[u]) : 0.f;
      ssum += ex;
      acc0 += ex * xl0[u];
      acc1 += ex * xl1[u];
    }
  }
  float inv = 1.f / (ssum + 1e-16f);
  *(unsigned*)(agg + (size_t)node * D + ch0) = pk2(acc0 * inv, acc1 * inv);
}

// ===== tier-2 eid-indirect fused =====
template <int H, int C>
__global__ __launch_bounds__(256) void k_fusedg(
    const int* __restrict__ start, const uint2* __restrict__ csr,
    const void* __restrict__ eattr, const int* __restrict__ flg,
    const float* __restrict__ mean_sums,
    const u16* __restrict__ xl, const u16* __restrict__ xr,
    const void* We, const void* att, u16* __restrict__ agg) {
  constexpr int D = H * C;
  constexpr int NPW = 64 / D;
  bool wb = flg[1] != 0;
  bool eb = flg[2] != 0;
  int lane = threadIdx.x & 63;
  int ch = lane % D;
  float Wreg[16];
  if (wb) {
    const u16* Wp = (const u16*)We;
#pragma unroll
    for (int k = 0; k < 16; k++) Wreg[k] = b2f(Wp[k * D + ch]);
  } else {
    const float* Wp = (const float*)We;
#pragma unroll
    for (int k = 0; k < 16; k++) Wreg[k] = Wp[k * D + ch];
  }
  float attv = wb ? b2f(((const u16*)att)[ch]) : ((const float*)att)[ch];
  float ev_self = 0.f;
#pragma unroll
  for (int k = 0; k < 16; k++) ev_self += mean_sums[k] * (1.0f / NE) * Wreg[k];
  int wid = (blockIdx.x * 256 + threadIdx.x) >> 6;
  int node = wid * NPW + lane / D;
  int s0 = start[node], s1 = start[node + 1];
  int deg = s1 - s0;
  int last = s1 - 1;
  int degmax = deg;
  if constexpr (NPW == 2) degmax = max(deg, __shfl_xor(deg, 32, 64));
  float xrv = b2f(xr[(size_t)node * D + ch]);
  float ssum = 0.f, acc = 0.f;
  for (int i = 0; i < degmax; i += 2) {
    uint2 cr0 = csr[min(s0 + i, last)];
    uint2 cr1 = csr[min(s0 + i + 1, last)];
    bool a0 = i < deg, a1 = i + 1 < deg;
    float xlv0 = b2f(xl[(size_t)cr0.x * D + ch]);
    float xlv1 = b2f(xl[(size_t)cr1.x * D + ch]);
    float ev0 = cr0.y < NE ? (eb ? dot16b((const u16*)eattr + (size_t)cr0.y * 16, Wreg)
                                 : dot16f((const float*)eattr + (size_t)cr0.y * 16, Wreg))
                           : ev_self;
    float ev1 = cr1.y < NE ? (eb ? dot16b((const u16*)eattr + (size_t)cr1.y * 16, Wreg)
                                 : dot16f((const float*)eattr + (size_t)cr1.y * 16, Wreg))
                           : ev_self;
    float mv0 = xlv0 + xrv + ev0;
    float mv1 = xlv1 + xrv + ev1;
    mv0 = (mv0 > 0.f) ? mv0 : 0.2f * mv0;
    mv1 = (mv1 > 0.f) ? mv1 : 0.2f * mv1;
    float t0 = mv0 * attv, t1 = mv1 * attv;
#pragma unroll
    for (int mk = 1; mk <= 16; mk <<= 1) {
      t0 += __shfl_xor(t0, mk, 64);
      t1 += __shfl_xor(t1, mk, 64);
    }
    float ex0 = a0 ? __expf(t0) : 0.f;
    float ex1 = a1 ? __expf(t1) : 0.f;
    ssum += ex0 + ex1;
    acc += ex0 * xlv0 + ex1 * xlv1;
  }
  agg[(size_t)node * D + ch] = f2b(acc / (ssum + 1e-16f));
}

// ========== batch-norm reduce ==========
template <int D>
__global__ __launch_bounds__(256) void k_bnred(const u16* __restrict__ v,
                                               float* __restrict__ sum,
                                               float* __restrict__ sq, int M) {
  constexpr int RB = 256 / D;
  int tid = threadIdx.x;
  int c = tid % D;
  int rg = tid / D;
  float s = 0.f, q = 0.f;
  for (int r = blockIdx.x * RB + rg; r < M; r += gridDim.x * RB) {
    float x = b2f(v[(size_t)r * D + c]);
    s += x;
    q += x * x;
  }
  __shared__ float ls[256], lq[256];
  ls[tid] = s; lq[tid] = q;
  __syncthreads();
  if (tid < D) {
    float ts = 0.f, tq = 0.f;
    for (int i = tid; i < 256; i += D) { ts += ls[i]; tq += lq[i]; }
    atomicAdd(&sum[tid], ts);
    atomicAdd(&sq[tid], tq);
  }
}

// ========== batch-norm apply + skip + ELU (layer 1) ==========
template <int D>
__global__ __launch_bounds__(256) void k_bnapply(const u16* __restrict__ agg,
                                                 const u16* __restrict__ hp,
                                                 const float* __restrict__ sum,
                                                 const float* __restrict__ sq,
                                                 const void* g, const void* b,
                                                 const int* __restrict__ flg,
                                                 u16* __restrict__ out, int M) {
  bool wb = flg[1] != 0;
  int idx = blockIdx.x * 256 + threadIdx.x;
  if (idx >= M * D) return;
  int c = idx & (D - 1);
  float gc = wb ? b2f(((const u16*)g)[c]) : ((const float*)g)[c];
  float bc = wb ? b2f(((const u16*)b)[c]) : ((const float*)b)[c];
  float mu = sum[c] * (1.f / M);
  float var = fmaxf(sq[c] * (1.f / M) - mu * mu, 0.f);
  float sc = rsqrtf(var + 1e-5f) * gc;
  float v = (b2f(agg[idx]) - mu) * sc + bc + b2f(hp[idx]);
  v = v > 0.f ? v : expm1f(v);
  out[idx] = f2b(v);
}

// ========== D11a: BN2-apply + ELU + pool into NPOOL privatized copies ==========
__global__ __launch_bounds__(256) void k_poolred(
    const u16* __restrict__ agg2, const u16* __restrict__ hp2,
    const float* __restrict__ sum, const float* __restrict__ sq,
    const void* g, const void* b, const int* __restrict__ flg,
    const int* __restrict__ batch,
    float* __restrict__ pool_sum, unsigned* __restrict__ pool_maxk,
    float* __restrict__ pool_cnt) {
  bool wb = flg[1] != 0;
  int c = threadIdx.x & 31;
  int rg = threadIdx.x >> 5;
  int cp = blockIdx.x & (NPOOL - 1);
  float* psum = pool_sum + cp * (NG * 32);
  unsigned* pmax = pool_maxk + cp * (NG * 32);
  float* pcnt = pool_cnt + cp * NG;
  float gc = wb ? b2f(((const u16*)g)[c]) : ((const float*)g)[c];
  float bc = wb ? b2f(((const u16*)b)[c]) : ((const float*)b)[c];
  float mu = sum[c] * (1.f / NN);
  float var = fmaxf(sq[c] * (1.f / NN) - mu * mu, 0.f);
  float scl = rsqrtf(var + 1e-5f) * gc;
  float sh = bc - mu * scl;

  const int NPB = 256;
  int n0 = blockIdx.x * NPB;
  int nend = min(n0 + NPB, NN);
  int cur = -1;
  float s = 0.f, mx = 0.f;
  int cnt = 0;
  for (int n = n0 + rg; n < nend; n += 8) {
    int gi = batch[n];
    float v = b2f(agg2[(size_t)n * 32 + c]) * scl + sh + b2f(hp2[(size_t)n * 32 + c]);
    v = v > 0.f ? v : expm1f(v);
    if (gi != cur) {
      if (cur >= 0) {
        atomicAdd(&psum[cur * 32 + c], s);
        atomicMax(&pmax[cur * 32 + c], f2key(mx));
        if (c == 0) atomicAdd(&pcnt[cur], (float)cnt);
      }
      cur = gi; s = 0.f; mx = -INFINITY; cnt = 0;
    }
    s += v;
    mx = fmaxf(mx, v);
    cnt++;
  }
  if (cur >= 0) {
    atomicAdd(&psum[cur * 32 + c], s);
    atomicMax(&pmax[cur * 32 + c], f2key(mx));
    if (c == 0) atomicAdd(&pcnt[cur], (float)cnt);
  }
}

// ========== D11b: reduce NPOOL copies -> output (1 block, plain loads) ==========
__global__ __launch_bounds__(256) void k_poolfin(
    const float* __restrict__ pool_sum, const unsigned* __restrict__ pool_maxk,
    const float* __restrict__ pool_cnt, const int* __restrict__ flg,
    void* __restrict__ out) {
  bool ob = flg[3] != 0;
  for (int idx = threadIdx.x; idx < NG * 64; idx += 256) {
    int gi = idx / 64, cc = idx % 64;
    float cntv = 0.f;
#pragma unroll
    for (int k = 0; k < NPOOL; k++) cntv += pool_cnt[k * NG + gi];
    float val;
    if (cc < 32) {
      float s = 0.f;
#pragma unroll
      for (int k = 0; k < NPOOL; k++) s += pool_sum[k * (NG * 32) + gi * 32 + cc];
      val = s / fmaxf(cntv, 1.f);
    } else {
      unsigned km = 0u;
#pragma unroll
      for (int k = 0; k < NPOOL; k++)
        km = max(km, pool_maxk[k * (NG * 32) + gi * 32 + (cc - 32)]);
      val = cntv > 0.f ? key2f(km) : 0.f;
    }
    if (ob) ((u16*)out)[idx] = f2b(val);
    else ((float*)out)[idx] = val;
  }
}

extern "C" void kernel_launch(void* const* d_in, const int* in_sizes, int n_in,
                              void* d_out, int out_size, void* d_ws, size_t ws_size,
                              hipStream_t stream) {
  (void)in_sizes; (void)n_in; (void)out_size;
  const void* x     = d_in[0];
  const int*  ei    = (const int*)d_in[1];
  const void* eattr = d_in[2];
  const int*  batch = (const int*)d_in[3];
  const void* skip1_W = d_in[4];
  const void* skip1_b = d_in[5];
  const void* c1_Wl = d_in[6];
  const void* c1_bl = d_in[7];
  const void* c1_Wr = d_in[8];
  const void* c1_br = d_in[9];
  const void* c1_We = d_in[10];
  const void* c1_att = d_in[11];
  const void* bn1_g = d_in[13];
  const void* bn1_b = d_in[14];
  const void* skip2_W = d_in[15];
  const void* skip2_b = d_in[16];
  const void* c2_Wl = d_in[17];
  const void* c2_bl = d_in[18];
  const void* c2_Wr = d_in[19];
  const void* c2_br = d_in[20];
  const void* c2_We = d_in[21];
  const void* c2_att = d_in[22];
  const void* bn2_g = d_in[24];
  const void* bn2_b = d_in[25];

  float* ws = (float*)d_ws;
  size_t off = 0;
  auto alloc = [&](size_t nfl) {
    float* p = ws + off;
    off += (nfl + 15) & ~(size_t)15;
    return p;
  };
  // ---- zero-initialized region ----
  int*   flags      = (int*)alloc(16);
  float* mean_sums  = alloc(16);
  float* mean_part  = alloc(64 * 16);
  int*   deg8       = (int*)alloc((size_t)NDEG * NN);
  float* bnsum1     = alloc(64);
  float* bnsq1      = alloc(64);
  float* bnsum2     = alloc(32);
  float* bnsq2      = alloc(32);
  float* pool_cnt   = alloc((size_t)NPOOL * NG);
  float* pool_sum   = alloc((size_t)NPOOL * NG * 32);
  unsigned* pool_maxk = (unsigned*)alloc((size_t)NPOOL * NG * 32);
  size_t zcnt16 = (off * sizeof(float)) / 16;
  // ---- common (not zeroed) ----
  int*   tile_tot = (int*)alloc(64);
  u16* xh  = (u16*)alloc((size_t)NN * 64);
  u16* xlo = (u16*)alloc((size_t)NN * 64);
  size_t zoff = off;

  // ---- tier 0: CSR payload + precomputed EW (~233 MB) ----
  int* start   = (int*)alloc(NN + 1);
  int* cursor  = (int*)alloc(NN);
  int* csr_src = (int*)alloc(ETOT);
  u16* ea16    = (u16*)alloc((size_t)ETOT * 8);
  u16* ew1     = (u16*)alloc((size_t)ETOT * 32);  // [ETOT][64] bf16
  u16* ew2     = (u16*)alloc((size_t)ETOT * 16);  // [ETOT][32] bf16
  uint2* csr = nullptr;
  u16* xl1 = (u16*)alloc((size_t)NN * 32);
  u16* xr1 = (u16*)alloc((size_t)NN * 32);
  u16* hp1 = (u16*)alloc((size_t)NN * 32);
  u16* agg = (u16*)alloc((size_t)NN * 32);
  int tier = 0;
  if (off * sizeof(float) > ws_size) {
    tier = 1;
    off = zoff;
    start   = (int*)alloc(NN + 1);
    cursor  = (int*)alloc(NN);
    csr_src = (int*)alloc(ETOT);
    ea16    = (u16*)alloc((size_t)ETOT * 8);
    ew1 = ew2 = nullptr;
    xl1 = (u16*)alloc((size_t)NN * 32);
    xr1 = (u16*)alloc((size_t)NN * 32);
    hp1 = (u16*)alloc((size_t)NN * 32);
    agg = (u16*)alloc((size_t)NN * 32);
  }
  if (tier == 1 && off * sizeof(float) > ws_size) {
    tier = 2;
    off = zoff;
    start   = (int*)alloc(NN + 1);
    cursor  = (int*)alloc(NN);
    csr     = (uint2*)alloc((size_t)ETOT * 2);
    ea16    = nullptr;
    xl1 = (u16*)alloc((size_t)NN * 32);
    xr1 = (u16*)alloc((size_t)NN * 32);
    hp1 = (u16*)alloc((size_t)NN * 32);
    agg = (u16*)alloc((size_t)NN * 32);
  }
  u16* h1  = xr1;
  u16* xl2 = xl1;
  u16* xr2 = xl1 + (size_t)NN * 32;
  u16* hp2 = hp1;

  int eg = (ETOT + 255) / 256;

  // D1: zero + detect
  k_init<<<128, 256, 0, stream>>>((uint4*)d_ws, (int)zcnt16,
                                  (const unsigned*)x, (const unsigned*)skip1_W,
                                  (const unsigned*)eattr, flags);
  // D2a: deg scatter (tiny waves, pure TLP)
  k_hist<<<eg, 256, 0, stream>>>(ei, deg8);
  // D2: colsum + x split (pure streaming)
  k_colsum_xsplit<<<2048, 256, 0, stream>>>(eattr, x, flags, mean_part, xh, xlo);
  // D2b: per-tile degree sums (parallel)
  k_scansum<<<SCAN_NT, 256, 0, stream>>>(deg8, mean_part, mean_sums, tile_tot);
  // D2c: prefix + write start/cursor (parallel)
  k_scanwrite<<<SCAN_NT, 256, 0, stream>>>(deg8, tile_tot, start, cursor);
  // D3: lin3 L1 (pure GEMM)
  k_lin1<128, 64, 625, 5><<<1875, 256, 0, stream>>>(
      x, xh, xlo, flags, c1_Wl, c1_Wr, skip1_W,
      c1_bl, c1_br, skip1_b, xl1, xr1, hp1);
  // D4: CSR build
  if (tier <= 1) {
    k_buildcsr_pay<<<eg, 256, 0, stream>>>(ei, eattr, flags, mean_sums,
                                           cursor, csr_src, ea16);
  } else {
    k_buildcsr<<<eg, 256, 0, stream>>>(ei, cursor, csr);
  }
  // D4c: EW precompute GEMM (tier 0 only)
  if (tier == 0) {
    k_ewgemm<<<1024, 256, 0, stream>>>(ea16, flags, c1_We, c2_We, ew1, ew2);
  }
  // D5: fused L1 (2ch/lane, 2 nodes/wave -> 8 nodes/block)
  if (tier == 0) {
    k_fusedp<2, 32, true><<<NN / 8, 256, 0, stream>>>(start, csr_src, ea16, ew1,
                                                      flags, xl1, xr1, c1_We,
                                                      c1_att, agg);
  } else if (tier == 1) {
    k_fusedp<2, 32, false><<<NN / 8, 256, 0, stream>>>(start, csr_src, ea16, nullptr,
                                                       flags, xl1, xr1, c1_We,
                                                       c1_att, agg);
  } else {
    k_fusedg<2, 32><<<NN / 4, 256, 0, stream>>>(start, csr, eattr, flags, mean_sums,
                                                xl1, xr1, c1_We, c1_att, agg);
  }
  // D6: bnred L1
  k_bnred<64><<<256, 256, 0, stream>>>(agg, bnsum1, bnsq1, NN);
  // D7: bn apply L1
  k_bnapply<64><<<(NN * 64 + 255) / 256, 256, 0, stream>>>(agg, hp1, bnsum1, bnsq1,
                                                           bn1_g, bn1_b, flags, h1, NN);
  // D8: lin3 L2 (LDS-free MFMA)
  {
    dim3 g(625, 3);
    k_lin3b<64, 32, 5><<<g, 256, 0, stream>>>(h1, flags, c2_Wl, c2_Wr, skip2_W,
                                              c2_bl, c2_br, skip2_b,
                                              xl2, xr2, hp2, NN);
  }
  // D9: fused L2 (2ch/lane, 4 nodes/wave -> 16 nodes/block)
  if (tier == 0) {
    k_fusedp<1, 32, true><<<NN / 16, 256, 0, stream>>>(start, csr_src, ea16, ew2,
                                                       flags, xl2, xr2, c2_We,
                                                       c2_att, agg);
  } else if (tier == 1) {
    k_fusedp<1, 32, false><<<NN / 16, 256, 0, stream>>>(start, csr_src, ea16, nullptr,
                                                        flags, xl2, xr2, c2_We,
                                                        c2_att, agg);
  } else {
    k_fusedg<1, 32><<<NN / 8, 256, 0, stream>>>(start, csr, eattr, flags, mean_sums,
                                                xl2, xr2, c2_We, c2_att, agg);
  }
  // D10: bnred L2
  k_bnred<32><<<256, 256, 0, stream>>>(agg, bnsum2, bnsq2, NN);
  // D11a: bn2 apply + pool into privatized copies (no fence)
  k_poolred<<<(NN + 255) / 256, 256, 0, stream>>>(agg, hp2, bnsum2, bnsq2,
                                                  bn2_g, bn2_b, flags, batch,
                                                  pool_sum, pool_maxk, pool_cnt);
  // D11b: reduce copies -> output (kernel-boundary visibility)
  k_poolfin<<<1, 256, 0, stream>>>(pool_sum, pool_maxk, pool_cnt, flags, d_out);
}